// Round 1
// baseline (265.419 us; speedup 1.0000x reference)
//
#include <hip/hip_runtime.h>
#include <hip/hip_bf16.h>

typedef __bf16 bf16;
typedef __bf16 bf16x8 __attribute__((ext_vector_type(8)));
typedef float f32x4 __attribute__((ext_vector_type(4)));

#define T_LEN 2048
#define NHEAD 16
#define DHEAD 64
#define CDIM 1024
#define NB 2

__device__ __forceinline__ void g2l16(const void* g, void* l) {
    __builtin_amdgcn_global_load_lds(
        (const __attribute__((address_space(1))) unsigned int*)g,
        (__attribute__((address_space(3))) unsigned int*)l, 16, 0, 0);
}

// ---------- fp32 -> bf16 convert, 8 elems/thread ----------
__global__ __launch_bounds__(256) void f2b_kernel(const float* __restrict__ in,
                                                  bf16* __restrict__ out, int n8) {
    int i = blockIdx.x * 256 + threadIdx.x;
    if (i >= n8) return;
    const float4* p = (const float4*)in + (size_t)i * 2;
    float4 a = p[0], b = p[1];
    bf16x8 o;
    o[0] = (bf16)a.x; o[1] = (bf16)a.y; o[2] = (bf16)a.z; o[3] = (bf16)a.w;
    o[4] = (bf16)b.x; o[5] = (bf16)b.y; o[6] = (bf16)b.z; o[7] = (bf16)b.w;
    ((bf16x8*)out)[i] = o;
}

// ---------- RoPE tables: cos/sin(t * 10000^(-2(d%32)/64)) ----------
__global__ __launch_bounds__(256) void rope_tab_kernel(float* __restrict__ ct,
                                                       float* __restrict__ st) {
    int i = blockIdx.x * 256 + threadIdx.x;   // i = t*64 + d
    int t = i >> 6, d = i & 63;
    float ex = (float)(2 * (d & 31)) / 64.0f;
    float inv = powf(10000.0f, -ex);
    float ang = (float)t * inv;
    ct[i] = cosf(ang);
    st[i] = sinf(ang);
}

// ---------- QKV GEMM: qkv = xb @ wb^T + bias, fused RoPE, scatter to q/k/v ----------
__global__ __launch_bounds__(256) void gemm_qkv_kernel(
    const bf16* __restrict__ xb, const bf16* __restrict__ wb,
    const float* __restrict__ bias,
    const float* __restrict__ ct, const float* __restrict__ st,
    bf16* __restrict__ qg, bf16* __restrict__ kg, bf16* __restrict__ vg) {
    __shared__ __align__(16) bf16 sA[128 * 64];
    __shared__ __align__(16) bf16 sB[128 * 64];
    int m0 = blockIdx.x * 128, n0 = blockIdx.y * 128;
    int t = threadIdx.x, w = t >> 6, l = t & 63;
    int wm = w >> 1, wn = w & 1;
    int l15 = l & 15, lhi = l >> 4;
    f32x4 acc[4][4] = {};
    int srow = t >> 3, sch = t & 7;
    for (int k0 = 0; k0 < CDIM; k0 += 64) {
#pragma unroll
        for (int i = 0; i < 4; i++) {
            int rr = i * 32 + srow;
            g2l16(xb + (size_t)(m0 + rr) * CDIM + k0 + sch * 8, sA + rr * 64 + sch * 8);
            g2l16(wb + (size_t)(n0 + rr) * CDIM + k0 + sch * 8, sB + rr * 64 + sch * 8);
        }
        __syncthreads();
#pragma unroll
        for (int ks = 0; ks < 64; ks += 32) {
            bf16x8 af[4], bfr[4];
#pragma unroll
            for (int mt = 0; mt < 4; mt++)
                af[mt] = *(const bf16x8*)(sA + (wm * 64 + mt * 16 + l15) * 64 + ks + lhi * 8);
#pragma unroll
            for (int nt = 0; nt < 4; nt++)
                bfr[nt] = *(const bf16x8*)(sB + (wn * 64 + nt * 16 + l15) * 64 + ks + lhi * 8);
#pragma unroll
            for (int mt = 0; mt < 4; mt++)
#pragma unroll
                for (int nt = 0; nt < 4; nt++)
                    acc[mt][nt] = __builtin_amdgcn_mfma_f32_16x16x32_bf16(
                        af[mt], bfr[nt], acc[mt][nt], 0, 0, 0);
        }
        __syncthreads();
    }
    // epilogue: bias + RoPE (Q,K) + scatter to [B][H][T][Dh] bf16
#pragma unroll
    for (int mt = 0; mt < 4; mt++) {
#pragma unroll
        for (int nt = 0; nt < 4; nt++) {
            int col = n0 + wn * 64 + nt * 16 + l15;
            int sec = col >> 10;          // 0=Q 1=K 2=V
            int cc = col & 1023;
            int h = cc >> 6, d = cc & 63;
            float cb = bias[col];
#pragma unroll
            for (int r = 0; r < 4; r++) {
                int rowm = m0 + wm * 64 + mt * 16 + lhi * 4 + r;  // token index
                int bb = rowm >> 11, tt = rowm & 2047;
                float v = acc[mt][nt][r] + cb;
                float p = __shfl_xor(v, 1);   // partner column (d^1)
                size_t oidx = (((size_t)(bb * NHEAD + h)) * T_LEN + tt) * DHEAD + d;
                if (sec == 2) {
                    vg[oidx] = (bf16)v;
                } else {
                    float cs = ct[tt * 64 + d], sn = st[tt * 64 + d];
                    float o = (d & 1) ? (v * cs + p * sn) : (v * cs - p * sn);
                    if (sec == 0) qg[oidx] = (bf16)(o * 0.125f);  // fold 1/sqrt(64)
                    else          kg[oidx] = (bf16)o;
                }
            }
        }
    }
}

// ---------- flash attention: per (b,h,64-row q tile) ----------
__global__ __launch_bounds__(256) void attn_kernel(
    const bf16* __restrict__ qg, const bf16* __restrict__ kg, const bf16* __restrict__ vg,
    const int* __restrict__ amask, bf16* __restrict__ yb) {
    __shared__ __align__(16) bf16 sK[64 * 72];
    __shared__ __align__(16) bf16 sVt[64 * 72];
    __shared__ __align__(16) bf16 sP[4 * 16 * 72];
    __shared__ float smask[64];
    int qt = (int)gridDim.x - 1 - (int)blockIdx.x;  // heavy tiles dispatch first
    int h = blockIdx.y, b = blockIdx.z;
    int q0 = qt * 64;
    int t = threadIdx.x, w = t >> 6, l = t & 63;
    int l15 = l & 15, lhi = l >> 4;
    const size_t head_off = ((size_t)(b * NHEAD + h)) * T_LEN * DHEAD;
    const bf16* qb = qg + head_off;
    const bf16* kb = kg + head_off;
    const bf16* vb = vg + head_off;
    bf16x8 qf[2];
    {
        int qr = q0 + w * 16 + l15;
        qf[0] = *(const bf16x8*)(qb + (size_t)qr * DHEAD + lhi * 8);
        qf[1] = *(const bf16x8*)(qb + (size_t)qr * DHEAD + 32 + lhi * 8);
    }
    float m_[4] = {-1e30f, -1e30f, -1e30f, -1e30f};
    float ls[4] = {0.f, 0.f, 0.f, 0.f};
    f32x4 accy[4] = {};
    int srow = t >> 3, sch = t & 7;
    for (int kv0 = 0; kv0 <= q0; kv0 += 64) {
#pragma unroll
        for (int i = 0; i < 2; i++) {
            int rr = i * 32 + srow;
            float4 kvv = *(const float4*)(kb + (size_t)(kv0 + rr) * DHEAD + sch * 8);
            *(float4*)(sK + rr * 72 + sch * 8) = kvv;
            float4 vvv = *(const float4*)(vb + (size_t)(kv0 + rr) * DHEAD + sch * 8);
            const bf16* vp = (const bf16*)&vvv;
#pragma unroll
            for (int j = 0; j < 8; j++) sVt[(sch * 8 + j) * 72 + rr] = vp[j];
        }
        if (t < 64) smask[t] = (amask[b * T_LEN + kv0 + t] != 0) ? 0.0f : -1e30f;
        __syncthreads();
        // S = Q K^T (Q pre-scaled by 0.125)
        f32x4 s[4] = {};
#pragma unroll
        for (int ct_ = 0; ct_ < 4; ct_++) {
#pragma unroll
            for (int ks = 0; ks < 2; ks++) {
                bf16x8 kf = *(const bf16x8*)(sK + (ct_ * 16 + l15) * 72 + ks * 32 + lhi * 8);
                s[ct_] = __builtin_amdgcn_mfma_f32_16x16x32_bf16(qf[ks], kf, s[ct_], 0, 0, 0);
            }
        }
        // mask + online softmax (rows (lhi*4+r) are lane-local across 16-lane groups)
#pragma unroll
        for (int r = 0; r < 4; r++) {
            int qrow = q0 + w * 16 + lhi * 4 + r;
            float mx = -1e30f;
#pragma unroll
            for (int ct_ = 0; ct_ < 4; ct_++) {
                int k = kv0 + ct_ * 16 + l15;
                float sv = s[ct_][r] + smask[ct_ * 16 + l15];
                if (k > qrow) sv = -1e30f;
                s[ct_][r] = sv;
                mx = fmaxf(mx, sv);
            }
#pragma unroll
            for (int off = 1; off < 16; off <<= 1)
                mx = fmaxf(mx, __shfl_xor(mx, off));
            float mn = fmaxf(m_[r], mx);
            float sc = __expf(m_[r] - mn);
            m_[r] = mn;
            float rs = 0.f;
#pragma unroll
            for (int ct_ = 0; ct_ < 4; ct_++) {
                float pp = __expf(s[ct_][r] - mn);
                s[ct_][r] = pp;
                rs += pp;
            }
#pragma unroll
            for (int off = 1; off < 16; off <<= 1)
                rs += __shfl_xor(rs, off);
            ls[r] = ls[r] * sc + rs;
#pragma unroll
            for (int dt = 0; dt < 4; dt++) accy[dt][r] *= sc;
        }
        // P -> LDS (A-fragment relayout), then PV
#pragma unroll
        for (int ct_ = 0; ct_ < 4; ct_++)
#pragma unroll
            for (int r = 0; r < 4; r++)
                sP[w * 1152 + (lhi * 4 + r) * 72 + ct_ * 16 + l15] = (bf16)s[ct_][r];
#pragma unroll
        for (int ks = 0; ks < 2; ks++) {
            bf16x8 pf = *(const bf16x8*)(sP + w * 1152 + l15 * 72 + ks * 32 + lhi * 8);
#pragma unroll
            for (int dt = 0; dt < 4; dt++) {
                bf16x8 vf = *(const bf16x8*)(sVt + (dt * 16 + l15) * 72 + ks * 32 + lhi * 8);
                accy[dt] = __builtin_amdgcn_mfma_f32_16x16x32_bf16(pf, vf, accy[dt], 0, 0, 0);
            }
        }
        __syncthreads();
    }
    // epilogue: y/l -> yb[B,T,C] bf16
#pragma unroll
    for (int r = 0; r < 4; r++) {
        float inv = ls[r] > 0.f ? 1.0f / ls[r] : 0.0f;
        int rowt = q0 + w * 16 + lhi * 4 + r;
        size_t obase = ((size_t)(b * T_LEN + rowt)) * CDIM + (size_t)h * DHEAD;
#pragma unroll
        for (int dt = 0; dt < 4; dt++)
            yb[obase + dt * 16 + l15] = (bf16)(accy[dt][r] * inv);
    }
}

// ---------- output GEMM: out = yb @ wob^T + out_b (fp32 out) ----------
__global__ __launch_bounds__(256) void gemm_out_kernel(
    const bf16* __restrict__ yb, const bf16* __restrict__ wb,
    const float* __restrict__ bias, float* __restrict__ out) {
    __shared__ __align__(16) bf16 sA[128 * 64];
    __shared__ __align__(16) bf16 sB[128 * 64];
    int m0 = blockIdx.x * 128, n0 = blockIdx.y * 128;
    int t = threadIdx.x, w = t >> 6, l = t & 63;
    int wm = w >> 1, wn = w & 1;
    int l15 = l & 15, lhi = l >> 4;
    f32x4 acc[4][4] = {};
    int srow = t >> 3, sch = t & 7;
    for (int k0 = 0; k0 < CDIM; k0 += 64) {
#pragma unroll
        for (int i = 0; i < 4; i++) {
            int rr = i * 32 + srow;
            g2l16(yb + (size_t)(m0 + rr) * CDIM + k0 + sch * 8, sA + rr * 64 + sch * 8);
            g2l16(wb + (size_t)(n0 + rr) * CDIM + k0 + sch * 8, sB + rr * 64 + sch * 8);
        }
        __syncthreads();
#pragma unroll
        for (int ks = 0; ks < 64; ks += 32) {
            bf16x8 af[4], bfr[4];
#pragma unroll
            for (int mt = 0; mt < 4; mt++)
                af[mt] = *(const bf16x8*)(sA + (wm * 64 + mt * 16 + l15) * 64 + ks + lhi * 8);
#pragma unroll
            for (int nt = 0; nt < 4; nt++)
                bfr[nt] = *(const bf16x8*)(sB + (wn * 64 + nt * 16 + l15) * 64 + ks + lhi * 8);
#pragma unroll
            for (int mt = 0; mt < 4; mt++)
#pragma unroll
                for (int nt = 0; nt < 4; nt++)
                    acc[mt][nt] = __builtin_amdgcn_mfma_f32_16x16x32_bf16(
                        af[mt], bfr[nt], acc[mt][nt], 0, 0, 0);
        }
        __syncthreads();
    }
#pragma unroll
    for (int mt = 0; mt < 4; mt++) {
#pragma unroll
        for (int nt = 0; nt < 4; nt++) {
            int col = n0 + wn * 64 + nt * 16 + l15;
            float cb = bias[col];
#pragma unroll
            for (int r = 0; r < 4; r++) {
                int rowm = m0 + wm * 64 + mt * 16 + lhi * 4 + r;
                out[(size_t)rowm * CDIM + col] = acc[mt][nt][r] + cb;
            }
        }
    }
}

extern "C" void kernel_launch(void* const* d_in, const int* in_sizes, int n_in,
                              void* d_out, int out_size, void* d_ws, size_t ws_size,
                              hipStream_t stream) {
    const float* x      = (const float*)d_in[0];
    const int*   amask  = (const int*)d_in[1];
    const float* qkv_w  = (const float*)d_in[2];
    const float* qkv_b  = (const float*)d_in[3];
    const float* out_w  = (const float*)d_in[4];
    const float* out_b  = (const float*)d_in[5];
    float* out = (float*)d_out;

    char* ws = (char*)d_ws;
    bf16* xb  = (bf16*)(ws);                        // 8 MB   (4096x1024)
    bf16* wqb = (bf16*)(ws + (8ull  << 20));        // 6 MB   (3072x1024)
    bf16* wob = (bf16*)(ws + (14ull << 20));        // 2 MB   (1024x1024)
    bf16* qg  = (bf16*)(ws + (16ull << 20));        // 8 MB   [B,H,T,Dh]
    bf16* kg  = (bf16*)(ws + (24ull << 20));        // 8 MB
    bf16* vg  = (bf16*)(ws + (32ull << 20));        // 8 MB
    bf16* yb  = (bf16*)(ws + (40ull << 20));        // 8 MB   (4096x1024)
    float* ctab = (float*)(ws + (48ull << 20));     // 512 KB (2048x64)
    float* stab = (float*)(ws + (48ull << 20) + (1ull << 19));

    f2b_kernel<<<2048, 256, 0, stream>>>(x, xb, 524288);        // 4M/8
    f2b_kernel<<<1536, 256, 0, stream>>>(qkv_w, wqb, 393216);   // 3M/8
    f2b_kernel<<<512, 256, 0, stream>>>(out_w, wob, 131072);    // 1M/8
    rope_tab_kernel<<<512, 256, 0, stream>>>(ctab, stab);

    gemm_qkv_kernel<<<dim3(32, 24), 256, 0, stream>>>(xb, wqb, qkv_b, ctab, stab, qg, kg, vg);
    attn_kernel<<<dim3(32, NHEAD, NB), 256, 0, stream>>>(qg, kg, vg, amask, yb);
    gemm_out_kernel<<<dim3(32, 8), 256, 0, stream>>>(yb, wob, out_b, out);
}

// Round 2
// 240.717 us; speedup vs baseline: 1.1026x; 1.1026x over previous
//
#include <hip/hip_runtime.h>
#include <hip/hip_bf16.h>

typedef __bf16 bf16;
typedef __bf16 bf16x8 __attribute__((ext_vector_type(8)));
typedef float f32x4 __attribute__((ext_vector_type(4)));

#define T_LEN 2048
#define NHEAD 16
#define DHEAD 64
#define CDIM 1024
#define NB 2

__device__ __forceinline__ void g2l16(const void* g, void* l) {
    __builtin_amdgcn_global_load_lds(
        (const __attribute__((address_space(1))) unsigned int*)g,
        (__attribute__((address_space(3))) unsigned int*)l, 16, 0, 0);
}

// stage a 64-row x 128-byte tile from global (row stride gstride elems) into
// linear LDS [64][128B] with XOR-swizzled content (source pre-swizzle, m173).
__device__ __forceinline__ void stage_swz(const bf16* __restrict__ g, size_t gstride,
                                          bf16* lds, int t) {
#pragma unroll
    for (int c = 0; c < 2; c++) {
        int off = c * 4096 + t * 16;              // phys byte offset in LDS
        int row = off >> 7;
        int lcol = (off & 127) ^ ((row & 7) << 4); // logical byte col in row
        g2l16(g + (size_t)row * gstride + (lcol >> 1), (char*)lds + off);
    }
}

__device__ __forceinline__ bf16x8 rd_swz(const bf16* lds, int row, int colB) {
    return *(const bf16x8*)((const char*)lds + row * 128 + (colB ^ ((row & 7) << 4)));
}

// ---------- fp32 -> bf16 convert, 8 elems/thread ----------
__global__ __launch_bounds__(256) void f2b_kernel(const float* __restrict__ in,
                                                  bf16* __restrict__ out, int n8) {
    int i = blockIdx.x * 256 + threadIdx.x;
    if (i >= n8) return;
    const float4* p = (const float4*)in + (size_t)i * 2;
    float4 a = p[0], b = p[1];
    bf16x8 o;
    o[0] = (bf16)a.x; o[1] = (bf16)a.y; o[2] = (bf16)a.z; o[3] = (bf16)a.w;
    o[4] = (bf16)b.x; o[5] = (bf16)b.y; o[6] = (bf16)b.z; o[7] = (bf16)b.w;
    ((bf16x8*)out)[i] = o;
}

// ---------- RoPE tables ----------
__global__ __launch_bounds__(256) void rope_tab_kernel(float* __restrict__ ct,
                                                       float* __restrict__ st) {
    int i = blockIdx.x * 256 + threadIdx.x;   // i = t*64 + d
    int t = i >> 6, d = i & 63;
    float ex = (float)(2 * (d & 31)) / 64.0f;
    float inv = powf(10000.0f, -ex);
    float ang = (float)t * inv;
    ct[i] = cosf(ang);
    st[i] = sinf(ang);
}

// ---------- QKV GEMM: fused bias + RoPE; Q,K -> [B][H][T][Dh], V -> [B][H][Dh][T] ----------
__global__ __launch_bounds__(256) void gemm_qkv_kernel(
    const bf16* __restrict__ xb, const bf16* __restrict__ wb,
    const float* __restrict__ bias,
    const float* __restrict__ ct, const float* __restrict__ st,
    bf16* __restrict__ qg, bf16* __restrict__ kg, bf16* __restrict__ vt) {
    __shared__ __align__(16) bf16 sA[128 * 64];
    __shared__ __align__(16) bf16 sB[128 * 64];
    int m0 = blockIdx.x * 128, n0 = blockIdx.y * 128;
    int t = threadIdx.x, w = t >> 6, l = t & 63;
    int wm = w >> 1, wn = w & 1;
    int l15 = l & 15, lhi = l >> 4;
    f32x4 acc[4][4] = {};
    int srow = t >> 3, sch = t & 7;
    for (int k0 = 0; k0 < CDIM; k0 += 64) {
#pragma unroll
        for (int i = 0; i < 4; i++) {
            int rr = i * 32 + srow;
            g2l16(xb + (size_t)(m0 + rr) * CDIM + k0 + sch * 8, sA + rr * 64 + sch * 8);
            g2l16(wb + (size_t)(n0 + rr) * CDIM + k0 + sch * 8, sB + rr * 64 + sch * 8);
        }
        __syncthreads();
#pragma unroll
        for (int ks = 0; ks < 64; ks += 32) {
            bf16x8 af[4], bfr[4];
#pragma unroll
            for (int mt = 0; mt < 4; mt++)
                af[mt] = *(const bf16x8*)(sA + (wm * 64 + mt * 16 + l15) * 64 + ks + lhi * 8);
#pragma unroll
            for (int nt = 0; nt < 4; nt++)
                bfr[nt] = *(const bf16x8*)(sB + (wn * 64 + nt * 16 + l15) * 64 + ks + lhi * 8);
#pragma unroll
            for (int mt = 0; mt < 4; mt++)
#pragma unroll
                for (int nt = 0; nt < 4; nt++)
                    acc[mt][nt] = __builtin_amdgcn_mfma_f32_16x16x32_bf16(
                        af[mt], bfr[nt], acc[mt][nt], 0, 0, 0);
        }
        __syncthreads();
    }
#pragma unroll
    for (int mt = 0; mt < 4; mt++) {
#pragma unroll
        for (int nt = 0; nt < 4; nt++) {
            int col = n0 + wn * 64 + nt * 16 + l15;
            int sec = col >> 10;          // 0=Q 1=K 2=V
            int cc = col & 1023;
            int h = cc >> 6, d = cc & 63;
            float cb = bias[col];
#pragma unroll
            for (int r = 0; r < 4; r++) {
                int rowm = m0 + wm * 64 + mt * 16 + lhi * 4 + r;
                int bb = rowm >> 11, tt = rowm & 2047;
                float v = acc[mt][nt][r] + cb;
                float p = __shfl_xor(v, 1);
                size_t hb = ((size_t)(bb * NHEAD + h)) * T_LEN * DHEAD;
                if (sec == 2) {
                    vt[hb + (size_t)d * T_LEN + tt] = (bf16)v;   // transposed per head
                } else {
                    float cs = ct[tt * 64 + d], sn = st[tt * 64 + d];
                    float o = (d & 1) ? (v * cs + p * sn) : (v * cs - p * sn);
                    size_t oidx = hb + (size_t)tt * DHEAD + d;
                    if (sec == 0) qg[oidx] = (bf16)(o * 0.125f);
                    else          kg[oidx] = (bf16)o;
                }
            }
        }
    }
}

// ---------- flash attention ----------
__global__ __launch_bounds__(256) void attn_kernel(
    const bf16* __restrict__ qg, const bf16* __restrict__ kg, const bf16* __restrict__ vt,
    const int* __restrict__ amask, bf16* __restrict__ yb) {
    __shared__ __align__(16) bf16 sK[2][64 * 64];
    __shared__ __align__(16) bf16 sV[2][64 * 64];
    __shared__ __align__(16) bf16 sP[4 * 16 * 72];
    int qt = (int)gridDim.x - 1 - (int)blockIdx.x;  // heavy tiles dispatch first
    int h = blockIdx.y, b = blockIdx.z;
    int q0 = qt * 64;
    int t = threadIdx.x, w = t >> 6, l = t & 63;
    int l15 = l & 15, lhi = l >> 4;
    const size_t head_off = ((size_t)(b * NHEAD + h)) * T_LEN * DHEAD;
    const bf16* qb = qg + head_off;
    const bf16* kb = kg + head_off;
    const bf16* vb = vt + head_off;                 // [Dh][T]
    const int* mrow = amask + b * T_LEN;
    bf16x8 qf[2];
    {
        int qr = q0 + w * 16 + l15;
        qf[0] = *(const bf16x8*)(qb + (size_t)qr * DHEAD + lhi * 8);
        qf[1] = *(const bf16x8*)(qb + (size_t)qr * DHEAD + 32 + lhi * 8);
    }
    float m_[4] = {-1e30f, -1e30f, -1e30f, -1e30f};
    float ls[4] = {0.f, 0.f, 0.f, 0.f};
    f32x4 accy[4] = {};
    stage_swz(kb, DHEAD, sK[0], t);
    stage_swz(vb, T_LEN, sV[0], t);
    __syncthreads();
    int cur = 0;
    for (int kv0 = 0; kv0 <= q0; kv0 += 64) {
        if (kv0 + 64 <= q0) {                       // prefetch next tile
            stage_swz(kb + (size_t)(kv0 + 64) * DHEAD, DHEAD, sK[cur ^ 1], t);
            stage_swz(vb + (kv0 + 64), T_LEN, sV[cur ^ 1], t);
        }
        int mv[4];
#pragma unroll
        for (int c = 0; c < 4; c++) mv[c] = mrow[kv0 + c * 16 + l15];
        // S = Q K^T (Q pre-scaled by 0.125)
        f32x4 s[4] = {};
#pragma unroll
        for (int c = 0; c < 4; c++)
#pragma unroll
            for (int ks = 0; ks < 2; ks++) {
                bf16x8 kf = rd_swz(sK[cur], c * 16 + l15, ks * 64 + lhi * 16);
                s[c] = __builtin_amdgcn_mfma_f32_16x16x32_bf16(qf[ks], kf, s[c], 0, 0, 0);
            }
        bool diag = (kv0 == q0);
#pragma unroll
        for (int r = 0; r < 4; r++) {
            int qrow = q0 + w * 16 + lhi * 4 + r;
            float mx = -1e30f;
#pragma unroll
            for (int c = 0; c < 4; c++) {
                float sv = s[c][r];
                if (mv[c] == 0) sv = -1e30f;
                if (diag && (kv0 + c * 16 + l15 > qrow)) sv = -1e30f;
                s[c][r] = sv;
                mx = fmaxf(mx, sv);
            }
#pragma unroll
            for (int off = 1; off < 16; off <<= 1)
                mx = fmaxf(mx, __shfl_xor(mx, off));
            float mn = fmaxf(m_[r], mx);
            float sc = __expf(m_[r] - mn);
            m_[r] = mn;
            float rs = 0.f;
#pragma unroll
            for (int c = 0; c < 4; c++) {
                float pp = __expf(s[c][r] - mn);
                s[c][r] = pp;
                rs += pp;
            }
#pragma unroll
            for (int off = 1; off < 16; off <<= 1)
                rs += __shfl_xor(rs, off);
            ls[r] = ls[r] * sc + rs;
#pragma unroll
            for (int dt = 0; dt < 4; dt++) accy[dt][r] *= sc;
        }
        // P -> LDS (A-fragment relayout, wave-private region), then PV
#pragma unroll
        for (int c = 0; c < 4; c++)
#pragma unroll
            for (int r = 0; r < 4; r++)
                sP[w * 1152 + (lhi * 4 + r) * 72 + c * 16 + l15] = (bf16)s[c][r];
#pragma unroll
        for (int ks = 0; ks < 2; ks++) {
            bf16x8 pf = *(const bf16x8*)(sP + w * 1152 + l15 * 72 + ks * 32 + lhi * 8);
#pragma unroll
            for (int dt = 0; dt < 4; dt++) {
                bf16x8 vf = rd_swz(sV[cur], dt * 16 + l15, ks * 64 + lhi * 16);
                accy[dt] = __builtin_amdgcn_mfma_f32_16x16x32_bf16(pf, vf, accy[dt], 0, 0, 0);
            }
        }
        __syncthreads();
        cur ^= 1;
    }
#pragma unroll
    for (int r = 0; r < 4; r++) {
        float inv = ls[r] > 0.f ? 1.0f / ls[r] : 0.0f;
        int rowt = q0 + w * 16 + lhi * 4 + r;
        size_t obase = ((size_t)(b * T_LEN + rowt)) * CDIM + (size_t)h * DHEAD;
#pragma unroll
        for (int dt = 0; dt < 4; dt++)
            yb[obase + dt * 16 + l15] = (bf16)(accy[dt][r] * inv);
    }
}

// ---------- output GEMM ----------
__global__ __launch_bounds__(256) void gemm_out_kernel(
    const bf16* __restrict__ yb, const bf16* __restrict__ wb,
    const float* __restrict__ bias, float* __restrict__ out) {
    __shared__ __align__(16) bf16 sA[128 * 64];
    __shared__ __align__(16) bf16 sB[128 * 64];
    int m0 = blockIdx.x * 128, n0 = blockIdx.y * 128;
    int t = threadIdx.x, w = t >> 6, l = t & 63;
    int wm = w >> 1, wn = w & 1;
    int l15 = l & 15, lhi = l >> 4;
    f32x4 acc[4][4] = {};
    int srow = t >> 3, sch = t & 7;
    for (int k0 = 0; k0 < CDIM; k0 += 64) {
#pragma unroll
        for (int i = 0; i < 4; i++) {
            int rr = i * 32 + srow;
            g2l16(yb + (size_t)(m0 + rr) * CDIM + k0 + sch * 8, sA + rr * 64 + sch * 8);
            g2l16(wb + (size_t)(n0 + rr) * CDIM + k0 + sch * 8, sB + rr * 64 + sch * 8);
        }
        __syncthreads();
#pragma unroll
        for (int ks = 0; ks < 64; ks += 32) {
            bf16x8 af[4], bfr[4];
#pragma unroll
            for (int mt = 0; mt < 4; mt++)
                af[mt] = *(const bf16x8*)(sA + (wm * 64 + mt * 16 + l15) * 64 + ks + lhi * 8);
#pragma unroll
            for (int nt = 0; nt < 4; nt++)
                bfr[nt] = *(const bf16x8*)(sB + (wn * 64 + nt * 16 + l15) * 64 + ks + lhi * 8);
#pragma unroll
            for (int mt = 0; mt < 4; mt++)
#pragma unroll
                for (int nt = 0; nt < 4; nt++)
                    acc[mt][nt] = __builtin_amdgcn_mfma_f32_16x16x32_bf16(
                        af[mt], bfr[nt], acc[mt][nt], 0, 0, 0);
        }
        __syncthreads();
    }
#pragma unroll
    for (int mt = 0; mt < 4; mt++) {
#pragma unroll
        for (int nt = 0; nt < 4; nt++) {
            int col = n0 + wn * 64 + nt * 16 + l15;
            float cb = bias[col];
#pragma unroll
            for (int r = 0; r < 4; r++) {
                int rowm = m0 + wm * 64 + mt * 16 + lhi * 4 + r;
                out[(size_t)rowm * CDIM + col] = acc[mt][nt][r] + cb;
            }
        }
    }
}

extern "C" void kernel_launch(void* const* d_in, const int* in_sizes, int n_in,
                              void* d_out, int out_size, void* d_ws, size_t ws_size,
                              hipStream_t stream) {
    const float* x      = (const float*)d_in[0];
    const int*   amask  = (const int*)d_in[1];
    const float* qkv_w  = (const float*)d_in[2];
    const float* qkv_b  = (const float*)d_in[3];
    const float* out_w  = (const float*)d_in[4];
    const float* out_b  = (const float*)d_in[5];
    float* out = (float*)d_out;

    char* ws = (char*)d_ws;
    bf16* xb  = (bf16*)(ws);                        // 8 MB   (4096x1024)
    bf16* wqb = (bf16*)(ws + (8ull  << 20));        // 6 MB   (3072x1024)
    bf16* wob = (bf16*)(ws + (14ull << 20));        // 2 MB   (1024x1024)
    bf16* qg  = (bf16*)(ws + (16ull << 20));        // 8 MB   [B,H,T,Dh]
    bf16* kg  = (bf16*)(ws + (24ull << 20));        // 8 MB   [B,H,T,Dh]
    bf16* vt  = (bf16*)(ws + (32ull << 20));        // 8 MB   [B,H,Dh,T]
    bf16* yb  = (bf16*)(ws + (40ull << 20));        // 8 MB   (4096x1024)
    float* ctab = (float*)(ws + (48ull << 20));     // 512 KB (2048x64)
    float* stab = (float*)(ws + (48ull << 20) + (1ull << 19));

    f2b_kernel<<<2048, 256, 0, stream>>>(x, xb, 524288);
    f2b_kernel<<<1536, 256, 0, stream>>>(qkv_w, wqb, 393216);
    f2b_kernel<<<512, 256, 0, stream>>>(out_w, wob, 131072);
    rope_tab_kernel<<<512, 256, 0, stream>>>(ctab, stab);

    gemm_qkv_kernel<<<dim3(32, 24), 256, 0, stream>>>(xb, wqb, qkv_b, ctab, stab, qg, kg, vt);
    attn_kernel<<<dim3(32, NHEAD, NB), 256, 0, stream>>>(qg, kg, vt, amask, yb);
    gemm_out_kernel<<<dim3(32, 8), 256, 0, stream>>>(yb, wob, out_b, out);
}

// Round 3
// 228.843 us; speedup vs baseline: 1.1598x; 1.0519x over previous
//
#include <hip/hip_runtime.h>
#include <hip/hip_bf16.h>

typedef __bf16 bf16;
typedef __bf16 bf16x8 __attribute__((ext_vector_type(8)));
typedef float f32x4 __attribute__((ext_vector_type(4)));

#define T_LEN 2048
#define NHEAD 16
#define DHEAD 64
#define CDIM 1024
#define NB 2

__device__ __forceinline__ void g2l16(const void* g, void* l) {
    __builtin_amdgcn_global_load_lds(
        (const __attribute__((address_space(1))) unsigned int*)g,
        (__attribute__((address_space(3))) unsigned int*)l, 16, 0, 0);
}

// stage a 64-row x 128-byte tile from global (row stride gstride elems) into
// linear LDS [64][128B] with XOR-swizzled content (source pre-swizzle, m173).
__device__ __forceinline__ void stage_swz(const bf16* __restrict__ g, size_t gstride,
                                          bf16* lds, int t) {
#pragma unroll
    for (int c = 0; c < 2; c++) {
        int off = c * 4096 + t * 16;              // phys byte offset in LDS
        int row = off >> 7;
        int lcol = (off & 127) ^ ((row & 7) << 4); // logical byte col in row
        g2l16(g + (size_t)row * gstride + (lcol >> 1), (char*)lds + off);
    }
}

__device__ __forceinline__ bf16x8 rd_swz(const bf16* lds, int row, int colB) {
    return *(const bf16x8*)((const char*)lds + row * 128 + (colB ^ ((row & 7) << 4)));
}

// ---------- fp32 -> bf16 convert, 8 elems/thread ----------
__global__ __launch_bounds__(256) void f2b_kernel(const float* __restrict__ in,
                                                  bf16* __restrict__ out, int n8) {
    int i = blockIdx.x * 256 + threadIdx.x;
    if (i >= n8) return;
    const float4* p = (const float4*)in + (size_t)i * 2;
    float4 a = p[0], b = p[1];
    bf16x8 o;
    o[0] = (bf16)a.x; o[1] = (bf16)a.y; o[2] = (bf16)a.z; o[3] = (bf16)a.w;
    o[4] = (bf16)b.x; o[5] = (bf16)b.y; o[6] = (bf16)b.z; o[7] = (bf16)b.w;
    ((bf16x8*)out)[i] = o;
}

// ---------- RoPE tables ----------
__global__ __launch_bounds__(256) void rope_tab_kernel(float* __restrict__ ct,
                                                       float* __restrict__ st) {
    int i = blockIdx.x * 256 + threadIdx.x;   // i = t*64 + d
    int t = i >> 6, d = i & 63;
    float ex = (float)(2 * (d & 31)) / 64.0f;
    float inv = powf(10000.0f, -ex);
    float ang = (float)t * inv;
    ct[i] = cosf(ang);
    st[i] = sinf(ang);
}

// ---------- QKV GEMM: fused bias + RoPE; Q,K -> [B][H][T][Dh], V -> [B][H][Dh][T] ----------
__global__ __launch_bounds__(256) void gemm_qkv_kernel(
    const bf16* __restrict__ xb, const bf16* __restrict__ wb,
    const float* __restrict__ bias,
    const float* __restrict__ ct, const float* __restrict__ st,
    bf16* __restrict__ qg, bf16* __restrict__ kg, bf16* __restrict__ vt) {
    __shared__ __align__(16) bf16 sA[128 * 64];
    __shared__ __align__(16) bf16 sB[128 * 64];
    int m0 = blockIdx.x * 128, n0 = blockIdx.y * 128;
    int t = threadIdx.x, w = t >> 6, l = t & 63;
    int wm = w >> 1, wn = w & 1;
    int l15 = l & 15, lhi = l >> 4;
    f32x4 acc[4][4] = {};
    int srow = t >> 3, sch = t & 7;
    for (int k0 = 0; k0 < CDIM; k0 += 64) {
#pragma unroll
        for (int i = 0; i < 4; i++) {
            int rr = i * 32 + srow;
            g2l16(xb + (size_t)(m0 + rr) * CDIM + k0 + sch * 8, sA + rr * 64 + sch * 8);
            g2l16(wb + (size_t)(n0 + rr) * CDIM + k0 + sch * 8, sB + rr * 64 + sch * 8);
        }
        __syncthreads();
#pragma unroll
        for (int ks = 0; ks < 64; ks += 32) {
            bf16x8 af[4], bfr[4];
#pragma unroll
            for (int mt = 0; mt < 4; mt++)
                af[mt] = *(const bf16x8*)(sA + (wm * 64 + mt * 16 + l15) * 64 + ks + lhi * 8);
#pragma unroll
            for (int nt = 0; nt < 4; nt++)
                bfr[nt] = *(const bf16x8*)(sB + (wn * 64 + nt * 16 + l15) * 64 + ks + lhi * 8);
#pragma unroll
            for (int mt = 0; mt < 4; mt++)
#pragma unroll
                for (int nt = 0; nt < 4; nt++)
                    acc[mt][nt] = __builtin_amdgcn_mfma_f32_16x16x32_bf16(
                        af[mt], bfr[nt], acc[mt][nt], 0, 0, 0);
        }
        __syncthreads();
    }
#pragma unroll
    for (int mt = 0; mt < 4; mt++) {
#pragma unroll
        for (int nt = 0; nt < 4; nt++) {
            int col = n0 + wn * 64 + nt * 16 + l15;
            int sec = col >> 10;          // 0=Q 1=K 2=V
            int cc = col & 1023;
            int h = cc >> 6, d = cc & 63;
            float cb = bias[col];
#pragma unroll
            for (int r = 0; r < 4; r++) {
                int rowm = m0 + wm * 64 + mt * 16 + lhi * 4 + r;
                int bb = rowm >> 11, tt = rowm & 2047;
                float v = acc[mt][nt][r] + cb;
                float p = __shfl_xor(v, 1);
                size_t hb = ((size_t)(bb * NHEAD + h)) * T_LEN * DHEAD;
                if (sec == 2) {
                    vt[hb + (size_t)d * T_LEN + tt] = (bf16)v;   // transposed per head
                } else {
                    float cs = ct[tt * 64 + d], sn = st[tt * 64 + d];
                    float o = (d & 1) ? (v * cs + p * sn) : (v * cs - p * sn);
                    size_t oidx = hb + (size_t)tt * DHEAD + d;
                    if (sec == 0) qg[oidx] = (bf16)(o * 0.125f);
                    else          kg[oidx] = (bf16)o;
                }
            }
        }
    }
}

// ---------- flash attention: QBLK=128, KV tile 64, XCD-clustered ----------
__global__ __launch_bounds__(256, 3) void attn_kernel(
    const bf16* __restrict__ qg, const bf16* __restrict__ kg, const bf16* __restrict__ vt,
    const int* __restrict__ amask, bf16* __restrict__ yb) {
    __shared__ __align__(16) bf16 sK[2][64 * 64];
    __shared__ __align__(16) bf16 sV[2][64 * 64];
    __shared__ __align__(16) bf16 sP[4 * 16 * 72];
    // XCD-aware remap: lin%8 = XCD (round-robin heuristic). Each XCD gets 4
    // (b,h) pairs (K/V working set 2 MB < 4 MB L2), heavy q-tiles first.
    int lin = blockIdx.x;                 // 512 blocks
    int xcd = lin & 7, idx = lin >> 3;    // idx 0..63
    int pair = xcd * 4 + (idx >> 4);      // 0..31
    int qt = 15 - (idx & 15);             // heavy first
    int h = pair & 15, b = pair >> 4;
    int q0 = qt * 128;
    int t = threadIdx.x, w = t >> 6, l = t & 63;
    int l15 = l & 15, lhi = l >> 4;
    const size_t head_off = ((size_t)(b * NHEAD + h)) * T_LEN * DHEAD;
    const bf16* qb = qg + head_off;
    const bf16* kb = kg + head_off;
    const bf16* vb = vt + head_off;                 // [Dh][T]
    const int* mrow = amask + b * T_LEN;
    bf16x8 qf[2][2];
#pragma unroll
    for (int mb = 0; mb < 2; mb++) {
        int qr = q0 + mb * 64 + w * 16 + l15;
        qf[mb][0] = *(const bf16x8*)(qb + (size_t)qr * DHEAD + lhi * 8);
        qf[mb][1] = *(const bf16x8*)(qb + (size_t)qr * DHEAD + 32 + lhi * 8);
    }
    float m_[2][4], ls[2][4];
    f32x4 accy[2][4] = {};
#pragma unroll
    for (int mb = 0; mb < 2; mb++)
#pragma unroll
        for (int r = 0; r < 4; r++) { m_[mb][r] = -1e30f; ls[mb][r] = 0.f; }
    stage_swz(kb, DHEAD, sK[0], t);
    stage_swz(vb, T_LEN, sV[0], t);
    __syncthreads();
    int cur = 0;
    const int kv_end = q0 + 64;
    for (int kv0 = 0; kv0 <= kv_end; kv0 += 64) {
        if (kv0 + 64 <= kv_end) {                   // prefetch next tile
            stage_swz(kb + (size_t)(kv0 + 64) * DHEAD, DHEAD, sK[cur ^ 1], t);
            stage_swz(vb + (kv0 + 64), T_LEN, sV[cur ^ 1], t);
        }
        int mv[4];
#pragma unroll
        for (int c = 0; c < 4; c++) mv[c] = mrow[kv0 + c * 16 + l15];
#pragma unroll
        for (int mb = 0; mb < 2; mb++) {
            int mq0 = q0 + mb * 64;
            if (kv0 > mq0) continue;                // fully masked (only mb=0, last iter)
            // S = Q K^T (Q pre-scaled by 0.125)
            f32x4 s[4] = {};
            __builtin_amdgcn_s_setprio(1);
#pragma unroll
            for (int c = 0; c < 4; c++)
#pragma unroll
                for (int ks = 0; ks < 2; ks++) {
                    bf16x8 kf = rd_swz(sK[cur], c * 16 + l15, ks * 64 + lhi * 16);
                    s[c] = __builtin_amdgcn_mfma_f32_16x16x32_bf16(qf[mb][ks], kf, s[c], 0, 0, 0);
                }
            __builtin_amdgcn_s_setprio(0);
            bool diag = (kv0 == mq0);
#pragma unroll
            for (int r = 0; r < 4; r++) {
                int qrow = mq0 + w * 16 + lhi * 4 + r;
                float mx = -1e30f;
#pragma unroll
                for (int c = 0; c < 4; c++) {
                    float sv = s[c][r];
                    if (mv[c] == 0) sv = -1e30f;
                    if (diag && (kv0 + c * 16 + l15 > qrow)) sv = -1e30f;
                    s[c][r] = sv;
                    mx = fmaxf(mx, sv);
                }
#pragma unroll
                for (int off = 1; off < 16; off <<= 1)
                    mx = fmaxf(mx, __shfl_xor(mx, off));
                float mn = fmaxf(m_[mb][r], mx);
                float sc = __expf(m_[mb][r] - mn);
                m_[mb][r] = mn;
                float rs = 0.f;
#pragma unroll
                for (int c = 0; c < 4; c++) {
                    float pp = __expf(s[c][r] - mn);
                    s[c][r] = pp;
                    rs += pp;
                }
#pragma unroll
                for (int off = 1; off < 16; off <<= 1)
                    rs += __shfl_xor(rs, off);
                ls[mb][r] = ls[mb][r] * sc + rs;
#pragma unroll
                for (int dt = 0; dt < 4; dt++) accy[mb][dt][r] *= sc;
            }
            // P -> LDS (A-fragment relayout, wave-private region), then PV
#pragma unroll
            for (int c = 0; c < 4; c++)
#pragma unroll
                for (int r = 0; r < 4; r++)
                    sP[w * 1152 + (lhi * 4 + r) * 72 + c * 16 + l15] = (bf16)s[c][r];
            __builtin_amdgcn_s_setprio(1);
#pragma unroll
            for (int ks = 0; ks < 2; ks++) {
                bf16x8 pf = *(const bf16x8*)(sP + w * 1152 + l15 * 72 + ks * 32 + lhi * 8);
#pragma unroll
                for (int dt = 0; dt < 4; dt++) {
                    bf16x8 vf = rd_swz(sV[cur], dt * 16 + l15, ks * 64 + lhi * 16);
                    accy[mb][dt] = __builtin_amdgcn_mfma_f32_16x16x32_bf16(pf, vf, accy[mb][dt], 0, 0, 0);
                }
            }
            __builtin_amdgcn_s_setprio(0);
        }
        __syncthreads();
        cur ^= 1;
    }
#pragma unroll
    for (int mb = 0; mb < 2; mb++)
#pragma unroll
        for (int r = 0; r < 4; r++) {
            float inv = ls[mb][r] > 0.f ? 1.0f / ls[mb][r] : 0.0f;
            int rowt = q0 + mb * 64 + w * 16 + lhi * 4 + r;
            size_t obase = ((size_t)(b * T_LEN + rowt)) * CDIM + (size_t)h * DHEAD;
#pragma unroll
            for (int dt = 0; dt < 4; dt++)
                yb[obase + dt * 16 + l15] = (bf16)(accy[mb][dt][r] * inv);
        }
}

// ---------- output GEMM ----------
__global__ __launch_bounds__(256) void gemm_out_kernel(
    const bf16* __restrict__ yb, const bf16* __restrict__ wb,
    const float* __restrict__ bias, float* __restrict__ out) {
    __shared__ __align__(16) bf16 sA[128 * 64];
    __shared__ __align__(16) bf16 sB[128 * 64];
    int m0 = blockIdx.x * 128, n0 = blockIdx.y * 128;
    int t = threadIdx.x, w = t >> 6, l = t & 63;
    int wm = w >> 1, wn = w & 1;
    int l15 = l & 15, lhi = l >> 4;
    f32x4 acc[4][4] = {};
    int srow = t >> 3, sch = t & 7;
    for (int k0 = 0; k0 < CDIM; k0 += 64) {
#pragma unroll
        for (int i = 0; i < 4; i++) {
            int rr = i * 32 + srow;
            g2l16(yb + (size_t)(m0 + rr) * CDIM + k0 + sch * 8, sA + rr * 64 + sch * 8);
            g2l16(wb + (size_t)(n0 + rr) * CDIM + k0 + sch * 8, sB + rr * 64 + sch * 8);
        }
        __syncthreads();
#pragma unroll
        for (int ks = 0; ks < 64; ks += 32) {
            bf16x8 af[4], bfr[4];
#pragma unroll
            for (int mt = 0; mt < 4; mt++)
                af[mt] = *(const bf16x8*)(sA + (wm * 64 + mt * 16 + l15) * 64 + ks + lhi * 8);
#pragma unroll
            for (int nt = 0; nt < 4; nt++)
                bfr[nt] = *(const bf16x8*)(sB + (wn * 64 + nt * 16 + l15) * 64 + ks + lhi * 8);
#pragma unroll
            for (int mt = 0; mt < 4; mt++)
#pragma unroll
                for (int nt = 0; nt < 4; nt++)
                    acc[mt][nt] = __builtin_amdgcn_mfma_f32_16x16x32_bf16(
                        af[mt], bfr[nt], acc[mt][nt], 0, 0, 0);
        }
        __syncthreads();
    }
#pragma unroll
    for (int mt = 0; mt < 4; mt++) {
#pragma unroll
        for (int nt = 0; nt < 4; nt++) {
            int col = n0 + wn * 64 + nt * 16 + l15;
            float cb = bias[col];
#pragma unroll
            for (int r = 0; r < 4; r++) {
                int rowm = m0 + wm * 64 + mt * 16 + lhi * 4 + r;
                out[(size_t)rowm * CDIM + col] = acc[mt][nt][r] + cb;
            }
        }
    }
}

extern "C" void kernel_launch(void* const* d_in, const int* in_sizes, int n_in,
                              void* d_out, int out_size, void* d_ws, size_t ws_size,
                              hipStream_t stream) {
    const float* x      = (const float*)d_in[0];
    const int*   amask  = (const int*)d_in[1];
    const float* qkv_w  = (const float*)d_in[2];
    const float* qkv_b  = (const float*)d_in[3];
    const float* out_w  = (const float*)d_in[4];
    const float* out_b  = (const float*)d_in[5];
    float* out = (float*)d_out;

    char* ws = (char*)d_ws;
    bf16* xb  = (bf16*)(ws);                        // 8 MB   (4096x1024)
    bf16* wqb = (bf16*)(ws + (8ull  << 20));        // 6 MB   (3072x1024)
    bf16* wob = (bf16*)(ws + (14ull << 20));        // 2 MB   (1024x1024)
    bf16* qg  = (bf16*)(ws + (16ull << 20));        // 8 MB   [B,H,T,Dh]
    bf16* kg  = (bf16*)(ws + (24ull << 20));        // 8 MB   [B,H,T,Dh]
    bf16* vt  = (bf16*)(ws + (32ull << 20));        // 8 MB   [B,H,Dh,T]
    bf16* yb  = (bf16*)(ws + (40ull << 20));        // 8 MB   (4096x1024)
    float* ctab = (float*)(ws + (48ull << 20));     // 512 KB (2048x64)
    float* stab = (float*)(ws + (48ull << 20) + (1ull << 19));

    f2b_kernel<<<2048, 256, 0, stream>>>(x, xb, 524288);
    f2b_kernel<<<1536, 256, 0, stream>>>(qkv_w, wqb, 393216);
    f2b_kernel<<<512, 256, 0, stream>>>(out_w, wob, 131072);
    rope_tab_kernel<<<512, 256, 0, stream>>>(ctab, stab);

    gemm_qkv_kernel<<<dim3(32, 24), 256, 0, stream>>>(xb, wqb, qkv_b, ctab, stab, qg, kg, vt);
    attn_kernel<<<dim3(512), 256, 0, stream>>>(qg, kg, vt, amask, yb);
    gemm_out_kernel<<<dim3(32, 8), 256, 0, stream>>>(yb, wob, out_b, out);
}

// Round 4
// 212.929 us; speedup vs baseline: 1.2465x; 1.0747x over previous
//
#include <hip/hip_runtime.h>
#include <hip/hip_bf16.h>

typedef __bf16 bf16;
typedef __bf16 bf16x8 __attribute__((ext_vector_type(8)));
typedef float f32x4 __attribute__((ext_vector_type(4)));

#define T_LEN 2048
#define NHEAD 16
#define DHEAD 64
#define CDIM 1024
#define NB 2

__device__ __forceinline__ void g2l16(const void* g, void* l) {
    __builtin_amdgcn_global_load_lds(
        (const __attribute__((address_space(1))) unsigned int*)g,
        (__attribute__((address_space(3))) unsigned int*)l, 16, 0, 0);
}

// stage a 64-row x 128-byte tile into linear LDS with XOR-swizzled content
// (source pre-swizzle, m173). 512 threads: one 16B chunk each.
__device__ __forceinline__ void stage_swz512(const bf16* __restrict__ g, size_t gstride,
                                             bf16* lds, int t) {
    int off = t * 16;                          // phys byte offset in LDS (0..8191)
    int row = off >> 7;
    int lcol = (off & 127) ^ ((row & 7) << 4); // logical byte col in row
    g2l16(g + (size_t)row * gstride + (lcol >> 1), (char*)lds + off);
}

__device__ __forceinline__ bf16x8 rd_swz(const bf16* lds, int row, int colB) {
    return *(const bf16x8*)((const char*)lds + row * 128 + (colB ^ ((row & 7) << 4)));
}

// ---------- fp32 -> bf16 convert, 8 elems/thread ----------
__global__ __launch_bounds__(256) void f2b_kernel(const float* __restrict__ in,
                                                  bf16* __restrict__ out, int n8) {
    int i = blockIdx.x * 256 + threadIdx.x;
    if (i >= n8) return;
    const float4* p = (const float4*)in + (size_t)i * 2;
    float4 a = p[0], b = p[1];
    bf16x8 o;
    o[0] = (bf16)a.x; o[1] = (bf16)a.y; o[2] = (bf16)a.z; o[3] = (bf16)a.w;
    o[4] = (bf16)b.x; o[5] = (bf16)b.y; o[6] = (bf16)b.z; o[7] = (bf16)b.w;
    ((bf16x8*)out)[i] = o;
}

// ---------- RoPE tables ----------
__global__ __launch_bounds__(256) void rope_tab_kernel(float* __restrict__ ct,
                                                       float* __restrict__ st) {
    int i = blockIdx.x * 256 + threadIdx.x;   // i = t*64 + d
    int t = i >> 6, d = i & 63;
    float ex = (float)(2 * (d & 31)) / 64.0f;
    float inv = powf(10000.0f, -ex);
    float ang = (float)t * inv;
    ct[i] = cosf(ang);
    st[i] = sinf(ang);
}

// ---------- QKV GEMM: fused bias + RoPE; Q,K -> [B][H][T][Dh], V -> [B][H][Dh][T] ----------
__global__ __launch_bounds__(256) void gemm_qkv_kernel(
    const bf16* __restrict__ xb, const bf16* __restrict__ wb,
    const float* __restrict__ bias,
    const float* __restrict__ ct, const float* __restrict__ st,
    bf16* __restrict__ qg, bf16* __restrict__ kg, bf16* __restrict__ vt) {
    __shared__ __align__(16) bf16 sA[128 * 64];
    __shared__ __align__(16) bf16 sB[128 * 64];
    int m0 = blockIdx.x * 128, n0 = blockIdx.y * 128;
    int t = threadIdx.x, w = t >> 6, l = t & 63;
    int wm = w >> 1, wn = w & 1;
    int l15 = l & 15, lhi = l >> 4;
    f32x4 acc[4][4] = {};
    int srow = t >> 3, sch = t & 7;
    for (int k0 = 0; k0 < CDIM; k0 += 64) {
#pragma unroll
        for (int i = 0; i < 4; i++) {
            int rr = i * 32 + srow;
            g2l16(xb + (size_t)(m0 + rr) * CDIM + k0 + sch * 8, sA + rr * 64 + sch * 8);
            g2l16(wb + (size_t)(n0 + rr) * CDIM + k0 + sch * 8, sB + rr * 64 + sch * 8);
        }
        __syncthreads();
#pragma unroll
        for (int ks = 0; ks < 64; ks += 32) {
            bf16x8 af[4], bfr[4];
#pragma unroll
            for (int mt = 0; mt < 4; mt++)
                af[mt] = *(const bf16x8*)(sA + (wm * 64 + mt * 16 + l15) * 64 + ks + lhi * 8);
#pragma unroll
            for (int nt = 0; nt < 4; nt++)
                bfr[nt] = *(const bf16x8*)(sB + (wn * 64 + nt * 16 + l15) * 64 + ks + lhi * 8);
#pragma unroll
            for (int mt = 0; mt < 4; mt++)
#pragma unroll
                for (int nt = 0; nt < 4; nt++)
                    acc[mt][nt] = __builtin_amdgcn_mfma_f32_16x16x32_bf16(
                        af[mt], bfr[nt], acc[mt][nt], 0, 0, 0);
        }
        __syncthreads();
    }
#pragma unroll
    for (int mt = 0; mt < 4; mt++) {
#pragma unroll
        for (int nt = 0; nt < 4; nt++) {
            int col = n0 + wn * 64 + nt * 16 + l15;
            int sec = col >> 10;          // 0=Q 1=K 2=V
            int cc = col & 1023;
            int h = cc >> 6, d = cc & 63;
            float cb = bias[col];
#pragma unroll
            for (int r = 0; r < 4; r++) {
                int rowm = m0 + wm * 64 + mt * 16 + lhi * 4 + r;
                int bb = rowm >> 11, tt = rowm & 2047;
                float v = acc[mt][nt][r] + cb;
                float p = __shfl_xor(v, 1);
                size_t hb = ((size_t)(bb * NHEAD + h)) * T_LEN * DHEAD;
                if (sec == 2) {
                    vt[hb + (size_t)d * T_LEN + tt] = (bf16)v;   // transposed per head
                } else {
                    float cs = ct[tt * 64 + d], sn = st[tt * 64 + d];
                    float o = (d & 1) ? (v * cs + p * sn) : (v * cs - p * sn);
                    size_t oidx = hb + (size_t)tt * DHEAD + d;
                    if (sec == 0) qg[oidx] = (bf16)(o * 0.125f);
                    else          kg[oidx] = (bf16)o;
                }
            }
        }
    }
}

// ---------- flash attention: 8 waves x 16-row strips, QBLK=128, XCD-clustered ----------
__global__ __launch_bounds__(512, 4) void attn_kernel(
    const bf16* __restrict__ qg, const bf16* __restrict__ kg, const bf16* __restrict__ vt,
    const int* __restrict__ amask, bf16* __restrict__ yb) {
    __shared__ __align__(16) bf16 sK[2][64 * 64];
    __shared__ __align__(16) bf16 sV[2][64 * 64];
    __shared__ __align__(16) bf16 sP[8 * 16 * 72];
    // XCD-aware remap: lin%8 = XCD. Each XCD gets 4 (b,h) pairs (K/V set
    // 2 MB < 4 MB L2). qt alternates heavy/light so co-resident blocks balance.
    int lin = blockIdx.x;                 // 512 blocks
    int xcd = lin & 7, idx = lin >> 3;    // idx 0..63
    int group = idx >> 4, pos = idx & 15;
    int qt = (pos & 1) ? (pos >> 1) : (15 - (pos >> 1));
    int pair = xcd * 4 + group;           // 0..31
    int h = pair & 15, b = pair >> 4;
    int q0 = qt * 128;
    int t = threadIdx.x, w = t >> 6, l = t & 63;
    int l15 = l & 15, lhi = l >> 4;
    const size_t head_off = ((size_t)(b * NHEAD + h)) * T_LEN * DHEAD;
    const bf16* qb = qg + head_off;
    const bf16* kb = kg + head_off;
    const bf16* vb = vt + head_off;                 // [Dh][T]
    const int* mrow = amask + b * T_LEN;
    const int wq0 = q0 + w * 16;                    // wave's first q row
    bf16x8 qf[2];
    {
        int qr = wq0 + l15;
        qf[0] = *(const bf16x8*)(qb + (size_t)qr * DHEAD + lhi * 8);
        qf[1] = *(const bf16x8*)(qb + (size_t)qr * DHEAD + 32 + lhi * 8);
    }
    float m_[4] = {-1e30f, -1e30f, -1e30f, -1e30f};
    float ls[4] = {0.f, 0.f, 0.f, 0.f};
    f32x4 accy[4] = {};
    stage_swz512(kb, DHEAD, sK[0], t);
    stage_swz512(vb, T_LEN, sV[0], t);
    __syncthreads();
    int cur = 0;
    const int kv_end = q0 + 64;                     // covers rows up to q0+127
    for (int kv0 = 0; kv0 <= kv_end; kv0 += 64) {
        if (kv0 + 64 <= kv_end) {                   // prefetch next tile
            stage_swz512(kb + (size_t)(kv0 + 64) * DHEAD, DHEAD, sK[cur ^ 1], t);
            stage_swz512(vb + (kv0 + 64), T_LEN, sV[cur ^ 1], t);
        }
        if (kv0 <= wq0 + 15) {                      // wave has unmasked work
            int mv[4];
#pragma unroll
            for (int c = 0; c < 4; c++) mv[c] = mrow[kv0 + c * 16 + l15];
            // S = Q K^T (Q pre-scaled by 0.125)
            f32x4 s[4] = {};
            __builtin_amdgcn_s_setprio(1);
#pragma unroll
            for (int c = 0; c < 4; c++)
#pragma unroll
                for (int ks = 0; ks < 2; ks++) {
                    bf16x8 kf = rd_swz(sK[cur], c * 16 + l15, ks * 64 + lhi * 16);
                    s[c] = __builtin_amdgcn_mfma_f32_16x16x32_bf16(qf[ks], kf, s[c], 0, 0, 0);
                }
            __builtin_amdgcn_s_setprio(0);
            bool diag = (kv0 + 63 > wq0);           // tile crosses this strip's diagonal
#pragma unroll
            for (int r = 0; r < 4; r++) {
                int qrow = wq0 + lhi * 4 + r;
                float mx = -1e30f;
#pragma unroll
                for (int c = 0; c < 4; c++) {
                    float sv = s[c][r];
                    if (mv[c] == 0) sv = -1e30f;
                    if (diag && (kv0 + c * 16 + l15 > qrow)) sv = -1e30f;
                    s[c][r] = sv;
                    mx = fmaxf(mx, sv);
                }
#pragma unroll
                for (int off = 1; off < 16; off <<= 1)
                    mx = fmaxf(mx, __shfl_xor(mx, off));
                float mn = fmaxf(m_[r], mx);
                float sc = __expf(m_[r] - mn);
                m_[r] = mn;
                float rs = 0.f;
#pragma unroll
                for (int c = 0; c < 4; c++) {
                    float pp = __expf(s[c][r] - mn);
                    s[c][r] = pp;
                    rs += pp;
                }
#pragma unroll
                for (int off = 1; off < 16; off <<= 1)
                    rs += __shfl_xor(rs, off);
                ls[r] = ls[r] * sc + rs;
#pragma unroll
                for (int dt = 0; dt < 4; dt++) accy[dt][r] *= sc;
            }
            // P -> LDS (A-fragment relayout, wave-private region), then PV
#pragma unroll
            for (int c = 0; c < 4; c++)
#pragma unroll
                for (int r = 0; r < 4; r++)
                    sP[w * 1152 + (lhi * 4 + r) * 72 + c * 16 + l15] = (bf16)s[c][r];
            __builtin_amdgcn_s_setprio(1);
#pragma unroll
            for (int ks = 0; ks < 2; ks++) {
                bf16x8 pf = *(const bf16x8*)(sP + w * 1152 + l15 * 72 + ks * 32 + lhi * 8);
#pragma unroll
                for (int dt = 0; dt < 4; dt++) {
                    bf16x8 vf = rd_swz(sV[cur], dt * 16 + l15, ks * 64 + lhi * 16);
                    accy[dt] = __builtin_amdgcn_mfma_f32_16x16x32_bf16(pf, vf, accy[dt], 0, 0, 0);
                }
            }
            __builtin_amdgcn_s_setprio(0);
        }
        __syncthreads();
        cur ^= 1;
    }
#pragma unroll
    for (int r = 0; r < 4; r++) {
        float inv = ls[r] > 0.f ? 1.0f / ls[r] : 0.0f;
        int rowt = wq0 + lhi * 4 + r;
        size_t obase = ((size_t)(b * T_LEN + rowt)) * CDIM + (size_t)h * DHEAD;
#pragma unroll
        for (int dt = 0; dt < 4; dt++)
            yb[obase + dt * 16 + l15] = (bf16)(accy[dt][r] * inv);
    }
}

// ---------- output GEMM ----------
__global__ __launch_bounds__(256) void gemm_out_kernel(
    const bf16* __restrict__ yb, const bf16* __restrict__ wb,
    const float* __restrict__ bias, float* __restrict__ out) {
    __shared__ __align__(16) bf16 sA[128 * 64];
    __shared__ __align__(16) bf16 sB[128 * 64];
    int m0 = blockIdx.x * 128, n0 = blockIdx.y * 128;
    int t = threadIdx.x, w = t >> 6, l = t & 63;
    int wm = w >> 1, wn = w & 1;
    int l15 = l & 15, lhi = l >> 4;
    f32x4 acc[4][4] = {};
    int srow = t >> 3, sch = t & 7;
    for (int k0 = 0; k0 < CDIM; k0 += 64) {
#pragma unroll
        for (int i = 0; i < 4; i++) {
            int rr = i * 32 + srow;
            g2l16(yb + (size_t)(m0 + rr) * CDIM + k0 + sch * 8, sA + rr * 64 + sch * 8);
            g2l16(wb + (size_t)(n0 + rr) * CDIM + k0 + sch * 8, sB + rr * 64 + sch * 8);
        }
        __syncthreads();
#pragma unroll
        for (int ks = 0; ks < 64; ks += 32) {
            bf16x8 af[4], bfr[4];
#pragma unroll
            for (int mt = 0; mt < 4; mt++)
                af[mt] = *(const bf16x8*)(sA + (wm * 64 + mt * 16 + l15) * 64 + ks + lhi * 8);
#pragma unroll
            for (int nt = 0; nt < 4; nt++)
                bfr[nt] = *(const bf16x8*)(sB + (wn * 64 + nt * 16 + l15) * 64 + ks + lhi * 8);
#pragma unroll
            for (int mt = 0; mt < 4; mt++)
#pragma unroll
                for (int nt = 0; nt < 4; nt++)
                    acc[mt][nt] = __builtin_amdgcn_mfma_f32_16x16x32_bf16(
                        af[mt], bfr[nt], acc[mt][nt], 0, 0, 0);
        }
        __syncthreads();
    }
#pragma unroll
    for (int mt = 0; mt < 4; mt++) {
#pragma unroll
        for (int nt = 0; nt < 4; nt++) {
            int col = n0 + wn * 64 + nt * 16 + l15;
            float cb = bias[col];
#pragma unroll
            for (int r = 0; r < 4; r++) {
                int rowm = m0 + wm * 64 + mt * 16 + lhi * 4 + r;
                out[(size_t)rowm * CDIM + col] = acc[mt][nt][r] + cb;
            }
        }
    }
}

extern "C" void kernel_launch(void* const* d_in, const int* in_sizes, int n_in,
                              void* d_out, int out_size, void* d_ws, size_t ws_size,
                              hipStream_t stream) {
    const float* x      = (const float*)d_in[0];
    const int*   amask  = (const int*)d_in[1];
    const float* qkv_w  = (const float*)d_in[2];
    const float* qkv_b  = (const float*)d_in[3];
    const float* out_w  = (const float*)d_in[4];
    const float* out_b  = (const float*)d_in[5];
    float* out = (float*)d_out;

    char* ws = (char*)d_ws;
    bf16* xb  = (bf16*)(ws);                        // 8 MB   (4096x1024)
    bf16* wqb = (bf16*)(ws + (8ull  << 20));        // 6 MB   (3072x1024)
    bf16* wob = (bf16*)(ws + (14ull << 20));        // 2 MB   (1024x1024)
    bf16* qg  = (bf16*)(ws + (16ull << 20));        // 8 MB   [B,H,T,Dh]
    bf16* kg  = (bf16*)(ws + (24ull << 20));        // 8 MB   [B,H,T,Dh]
    bf16* vt  = (bf16*)(ws + (32ull << 20));        // 8 MB   [B,H,Dh,T]
    bf16* yb  = (bf16*)(ws + (40ull << 20));        // 8 MB   (4096x1024)
    float* ctab = (float*)(ws + (48ull << 20));     // 512 KB (2048x64)
    float* stab = (float*)(ws + (48ull << 20) + (1ull << 19));

    f2b_kernel<<<2048, 256, 0, stream>>>(x, xb, 524288);
    f2b_kernel<<<1536, 256, 0, stream>>>(qkv_w, wqb, 393216);
    f2b_kernel<<<512, 256, 0, stream>>>(out_w, wob, 131072);
    rope_tab_kernel<<<512, 256, 0, stream>>>(ctab, stab);

    gemm_qkv_kernel<<<dim3(32, 24), 256, 0, stream>>>(xb, wqb, qkv_b, ctab, stab, qg, kg, vt);
    attn_kernel<<<dim3(512), 512, 0, stream>>>(qg, kg, vt, amask, yb);
    gemm_out_kernel<<<dim3(32, 8), 256, 0, stream>>>(yb, wob, out_b, out);
}

// Round 5
// 183.071 us; speedup vs baseline: 1.4498x; 1.1631x over previous
//
#include <hip/hip_runtime.h>
#include <hip/hip_bf16.h>

typedef __bf16 bf16;
typedef __bf16 bf16x4 __attribute__((ext_vector_type(4)));
typedef __bf16 bf16x8 __attribute__((ext_vector_type(8)));
typedef float f32x4 __attribute__((ext_vector_type(4)));

#define T_LEN 2048
#define NHEAD 16
#define DHEAD 64
#define CDIM 1024
#define NB 2

__device__ __forceinline__ void g2l16(const void* g, void* l) {
    __builtin_amdgcn_global_load_lds(
        (const __attribute__((address_space(1))) unsigned int*)g,
        (__attribute__((address_space(3))) unsigned int*)l, 16, 0, 0);
}

// stage a 64-row x 128-byte tile into linear LDS with XOR-swizzled content
// (source pre-swizzle, m173). 512 threads: one 16B chunk each.
__device__ __forceinline__ void stage_swz512(const bf16* __restrict__ g, size_t gstride,
                                             bf16* lds, int t) {
    int off = t * 16;                          // phys byte offset in LDS (0..8191)
    int row = off >> 7;
    int lcol = (off & 127) ^ ((row & 7) << 4); // logical byte col in row
    g2l16(g + (size_t)row * gstride + (lcol >> 1), (char*)lds + off);
}

__device__ __forceinline__ bf16x8 rd_swz(const bf16* lds, int row, int colB) {
    return *(const bf16x8*)((const char*)lds + row * 128 + (colB ^ ((row & 7) << 4)));
}

// ---------- fp32 -> bf16 convert, 8 elems/thread ----------
__global__ __launch_bounds__(256) void f2b_kernel(const float* __restrict__ in,
                                                  bf16* __restrict__ out, int n8) {
    int i = blockIdx.x * 256 + threadIdx.x;
    if (i >= n8) return;
    const float4* p = (const float4*)in + (size_t)i * 2;
    float4 a = p[0], b = p[1];
    bf16x8 o;
    o[0] = (bf16)a.x; o[1] = (bf16)a.y; o[2] = (bf16)a.z; o[3] = (bf16)a.w;
    o[4] = (bf16)b.x; o[5] = (bf16)b.y; o[6] = (bf16)b.z; o[7] = (bf16)b.w;
    ((bf16x8*)out)[i] = o;
}

// ---------- RoPE tables ----------
__global__ __launch_bounds__(256) void rope_tab_kernel(float* __restrict__ ct,
                                                       float* __restrict__ st) {
    int i = blockIdx.x * 256 + threadIdx.x;   // i = t*64 + d
    int t = i >> 6, d = i & 63;
    float ex = (float)(2 * (d & 31)) / 64.0f;
    float inv = powf(10000.0f, -ex);
    float ang = (float)t * inv;
    ct[i] = cosf(ang);
    st[i] = sinf(ang);
}

// ---------- key mask -> additive float ----------
__global__ __launch_bounds__(256) void maskf_kernel(const int* __restrict__ am,
                                                    float* __restrict__ mf) {
    int i = blockIdx.x * 256 + threadIdx.x;   // 0..NB*T_LEN
    mf[i] = (am[i] != 0) ? 0.0f : -1e30f;
}

// ---------- QKV GEMM: fused bias + RoPE; Q,K -> [B][H][T][Dh], V -> [B][H][Dh][T] ----------
__global__ __launch_bounds__(256) void gemm_qkv_kernel(
    const bf16* __restrict__ xb, const bf16* __restrict__ wb,
    const float* __restrict__ bias,
    const float* __restrict__ ct, const float* __restrict__ st,
    bf16* __restrict__ qg, bf16* __restrict__ kg, bf16* __restrict__ vt) {
    __shared__ __align__(16) bf16 sA[128 * 64];
    __shared__ __align__(16) bf16 sB[128 * 64];
    int m0 = blockIdx.x * 128, n0 = blockIdx.y * 128;
    int t = threadIdx.x, w = t >> 6, l = t & 63;
    int wm = w >> 1, wn = w & 1;
    int l15 = l & 15, lhi = l >> 4;
    f32x4 acc[4][4] = {};
    int srow = t >> 3, sch = t & 7;
    for (int k0 = 0; k0 < CDIM; k0 += 64) {
#pragma unroll
        for (int i = 0; i < 4; i++) {
            int rr = i * 32 + srow;
            g2l16(xb + (size_t)(m0 + rr) * CDIM + k0 + sch * 8, sA + rr * 64 + sch * 8);
            g2l16(wb + (size_t)(n0 + rr) * CDIM + k0 + sch * 8, sB + rr * 64 + sch * 8);
        }
        __syncthreads();
#pragma unroll
        for (int ks = 0; ks < 64; ks += 32) {
            bf16x8 af[4], bfr[4];
#pragma unroll
            for (int mt = 0; mt < 4; mt++)
                af[mt] = *(const bf16x8*)(sA + (wm * 64 + mt * 16 + l15) * 64 + ks + lhi * 8);
#pragma unroll
            for (int nt = 0; nt < 4; nt++)
                bfr[nt] = *(const bf16x8*)(sB + (wn * 64 + nt * 16 + l15) * 64 + ks + lhi * 8);
#pragma unroll
            for (int mt = 0; mt < 4; mt++)
#pragma unroll
                for (int nt = 0; nt < 4; nt++)
                    acc[mt][nt] = __builtin_amdgcn_mfma_f32_16x16x32_bf16(
                        af[mt], bfr[nt], acc[mt][nt], 0, 0, 0);
        }
        __syncthreads();
    }
#pragma unroll
    for (int mt = 0; mt < 4; mt++) {
#pragma unroll
        for (int nt = 0; nt < 4; nt++) {
            int col = n0 + wn * 64 + nt * 16 + l15;
            int sec = col >> 10;          // 0=Q 1=K 2=V
            int cc = col & 1023;
            int h = cc >> 6, d = cc & 63;
            float cb = bias[col];
#pragma unroll
            for (int r = 0; r < 4; r++) {
                int rowm = m0 + wm * 64 + mt * 16 + lhi * 4 + r;
                int bb = rowm >> 11, tt = rowm & 2047;
                float v = acc[mt][nt][r] + cb;
                float p = __shfl_xor(v, 1);
                size_t hb = ((size_t)(bb * NHEAD + h)) * T_LEN * DHEAD;
                if (sec == 2) {
                    vt[hb + (size_t)d * T_LEN + tt] = (bf16)v;   // transposed per head
                } else {
                    float cs = ct[tt * 64 + d], sn = st[tt * 64 + d];
                    float o = (d & 1) ? (v * cs + p * sn) : (v * cs - p * sn);
                    size_t oidx = hb + (size_t)tt * DHEAD + d;
                    if (sec == 0) qg[oidx] = (bf16)(o * 0.125f);
                    else          kg[oidx] = (bf16)o;
                }
            }
        }
    }
}

// ---------- flash attention: swapped QK^T, per-lane-q softmax ----------
__global__ __launch_bounds__(512, 4) void attn_kernel(
    const bf16* __restrict__ qg, const bf16* __restrict__ kg, const bf16* __restrict__ vt,
    const float* __restrict__ maskf, bf16* __restrict__ yb) {
    __shared__ __align__(16) bf16 sK[2][64 * 64];
    __shared__ __align__(16) bf16 sV[2][64 * 64];
    __shared__ __align__(16) bf16 sP[8 * 16 * 72];
    int lin = blockIdx.x;                 // 512 blocks
    int xcd = lin & 7, idx = lin >> 3;    // idx 0..63
    int group = idx >> 4, pos = idx & 15;
    int qt = (pos & 1) ? (pos >> 1) : (15 - (pos >> 1));
    int pair = xcd * 4 + group;           // 0..31
    int h = pair & 15, b = pair >> 4;
    int q0 = qt * 128;
    int t = threadIdx.x, w = t >> 6, l = t & 63;
    int l15 = l & 15, lhi = l >> 4;
    const size_t head_off = ((size_t)(b * NHEAD + h)) * T_LEN * DHEAD;
    const bf16* qb = qg + head_off;
    const bf16* kb = kg + head_off;
    const bf16* vb = vt + head_off;                 // [Dh][T]
    const float* mrow = maskf + b * T_LEN;
    const int wq0 = q0 + w * 16;                    // wave's first q row
    const int qrow_l = wq0 + l15;                   // this lane's q row
    bf16* sPw = sP + w * 1152;
    bf16x8 qf[2];
    {
        qf[0] = *(const bf16x8*)(qb + (size_t)qrow_l * DHEAD + lhi * 8);
        qf[1] = *(const bf16x8*)(qb + (size_t)qrow_l * DHEAD + 32 + lhi * 8);
    }
    float m_ = -1e30f, ls = 0.f;                    // per-lane (q = l15)
    f32x4 accy[4] = {};
    stage_swz512(kb, DHEAD, sK[0], t);
    stage_swz512(vb, T_LEN, sV[0], t);
    __syncthreads();
    int cur = 0;
    const int kv_end = q0 + 64;                     // covers rows up to q0+127
    for (int kv0 = 0; kv0 <= kv_end; kv0 += 64) {
        if (kv0 + 64 <= kv_end) {                   // prefetch next tile
            stage_swz512(kb + (size_t)(kv0 + 64) * DHEAD, DHEAD, sK[cur ^ 1], t);
            stage_swz512(vb + (kv0 + 64), T_LEN, sV[cur ^ 1], t);
        }
        if (kv0 <= wq0 + 15) {                      // wave has unmasked work
            float4 mqv[4];
#pragma unroll
            for (int c = 0; c < 4; c++)
                mqv[c] = *(const float4*)(mrow + kv0 + c * 16 + lhi * 4);
            // S^T = K Q^T: lane holds q = l15, kv = c*16 + lhi*4 + r
            f32x4 s[4] = {};
            __builtin_amdgcn_s_setprio(1);
#pragma unroll
            for (int c = 0; c < 4; c++)
#pragma unroll
                for (int ks = 0; ks < 2; ks++) {
                    bf16x8 kf = rd_swz(sK[cur], c * 16 + l15, ks * 64 + lhi * 16);
                    s[c] = __builtin_amdgcn_mfma_f32_16x16x32_bf16(kf, qf[ks], s[c], 0, 0, 0);
                }
            __builtin_amdgcn_s_setprio(0);
            bool diag = (kv0 + 63 > wq0);           // tile crosses this strip's diagonal
            float mx = -1e30f;
#pragma unroll
            for (int c = 0; c < 4; c++) {
                const float* mp = (const float*)&mqv[c];
#pragma unroll
                for (int r = 0; r < 4; r++) {
                    float sv = s[c][r] + mp[r];
                    if (diag && (kv0 + c * 16 + lhi * 4 + r > qrow_l)) sv = -1e30f;
                    s[c][r] = sv;
                    mx = fmaxf(mx, sv);
                }
            }
            mx = fmaxf(mx, __shfl_xor(mx, 16));
            mx = fmaxf(mx, __shfl_xor(mx, 32));
            bool noresc = __all(mx <= m_ + 8.f);    // defer-max (T13, THR=8)
            float mn = m_, scf = 1.f;
            if (!noresc) {
                mn = fmaxf(m_, mx);
                scf = __expf(m_ - mn);
                m_ = mn;
            }
            float rs = 0.f;
#pragma unroll
            for (int c = 0; c < 4; c++)
#pragma unroll
                for (int r = 0; r < 4; r++) {
                    float pp = __expf(s[c][r] - mn);
                    s[c][r] = pp;
                    rs += pp;
                }
            rs += __shfl_xor(rs, 16);
            rs += __shfl_xor(rs, 32);
            if (noresc) {
                ls += rs;
            } else {
                ls = ls * scf + rs;
#pragma unroll
                for (int r = 0; r < 4; r++) {
                    // accy row r belongs to q = lhi*4+r; scf for it lives in lane
                    // (same 16-group, l15 = lhi*4+r)
                    float sr = __shfl(scf, (l & 48) + lhi * 4 + r);
#pragma unroll
                    for (int dt = 0; dt < 4; dt++) accy[dt][r] *= sr;
                }
            }
            // P -> sP[q=l15][kv], 4x ds_write_b64 (kv r=0..3 contiguous)
#pragma unroll
            for (int c = 0; c < 4; c++) {
                bf16x4 pv;
#pragma unroll
                for (int r = 0; r < 4; r++) pv[r] = (bf16)s[c][r];
                *(bf16x4*)(sPw + l15 * 72 + c * 16 + lhi * 4) = pv;
            }
            __builtin_amdgcn_s_setprio(1);
#pragma unroll
            for (int ks = 0; ks < 2; ks++) {
                bf16x8 pf = *(const bf16x8*)(sPw + l15 * 72 + ks * 32 + lhi * 8);
#pragma unroll
                for (int dt = 0; dt < 4; dt++) {
                    bf16x8 vf = rd_swz(sV[cur], dt * 16 + l15, ks * 64 + lhi * 16);
                    accy[dt] = __builtin_amdgcn_mfma_f32_16x16x32_bf16(pf, vf, accy[dt], 0, 0, 0);
                }
            }
            __builtin_amdgcn_s_setprio(0);
        }
        __syncthreads();
        cur ^= 1;
    }
#pragma unroll
    for (int r = 0; r < 4; r++) {
        float lsr = __shfl(ls, (l & 48) + lhi * 4 + r);
        float inv = lsr > 0.f ? 1.0f / lsr : 0.0f;
        int rowt = wq0 + lhi * 4 + r;
        size_t obase = ((size_t)(b * T_LEN + rowt)) * CDIM + (size_t)h * DHEAD;
#pragma unroll
        for (int dt = 0; dt < 4; dt++)
            yb[obase + dt * 16 + l15] = (bf16)(accy[dt][r] * inv);
    }
}

// ---------- output GEMM ----------
__global__ __launch_bounds__(256) void gemm_out_kernel(
    const bf16* __restrict__ yb, const bf16* __restrict__ wb,
    const float* __restrict__ bias, float* __restrict__ out) {
    __shared__ __align__(16) bf16 sA[128 * 64];
    __shared__ __align__(16) bf16 sB[128 * 64];
    int m0 = blockIdx.x * 128, n0 = blockIdx.y * 128;
    int t = threadIdx.x, w = t >> 6, l = t & 63;
    int wm = w >> 1, wn = w & 1;
    int l15 = l & 15, lhi = l >> 4;
    f32x4 acc[4][4] = {};
    int srow = t >> 3, sch = t & 7;
    for (int k0 = 0; k0 < CDIM; k0 += 64) {
#pragma unroll
        for (int i = 0; i < 4; i++) {
            int rr = i * 32 + srow;
            g2l16(yb + (size_t)(m0 + rr) * CDIM + k0 + sch * 8, sA + rr * 64 + sch * 8);
            g2l16(wb + (size_t)(n0 + rr) * CDIM + k0 + sch * 8, sB + rr * 64 + sch * 8);
        }
        __syncthreads();
#pragma unroll
        for (int ks = 0; ks < 64; ks += 32) {
            bf16x8 af[4], bfr[4];
#pragma unroll
            for (int mt = 0; mt < 4; mt++)
                af[mt] = *(const bf16x8*)(sA + (wm * 64 + mt * 16 + l15) * 64 + ks + lhi * 8);
#pragma unroll
            for (int nt = 0; nt < 4; nt++)
                bfr[nt] = *(const bf16x8*)(sB + (wn * 64 + nt * 16 + l15) * 64 + ks + lhi * 8);
#pragma unroll
            for (int mt = 0; mt < 4; mt++)
#pragma unroll
                for (int nt = 0; nt < 4; nt++)
                    acc[mt][nt] = __builtin_amdgcn_mfma_f32_16x16x32_bf16(
                        af[mt], bfr[nt], acc[mt][nt], 0, 0, 0);
        }
        __syncthreads();
    }
#pragma unroll
    for (int mt = 0; mt < 4; mt++) {
#pragma unroll
        for (int nt = 0; nt < 4; nt++) {
            int col = n0 + wn * 64 + nt * 16 + l15;
            float cb = bias[col];
#pragma unroll
            for (int r = 0; r < 4; r++) {
                int rowm = m0 + wm * 64 + mt * 16 + lhi * 4 + r;
                out[(size_t)rowm * CDIM + col] = acc[mt][nt][r] + cb;
            }
        }
    }
}

extern "C" void kernel_launch(void* const* d_in, const int* in_sizes, int n_in,
                              void* d_out, int out_size, void* d_ws, size_t ws_size,
                              hipStream_t stream) {
    const float* x      = (const float*)d_in[0];
    const int*   amask  = (const int*)d_in[1];
    const float* qkv_w  = (const float*)d_in[2];
    const float* qkv_b  = (const float*)d_in[3];
    const float* out_w  = (const float*)d_in[4];
    const float* out_b  = (const float*)d_in[5];
    float* out = (float*)d_out;

    char* ws = (char*)d_ws;
    bf16* xb  = (bf16*)(ws);                        // 8 MB   (4096x1024)
    bf16* wqb = (bf16*)(ws + (8ull  << 20));        // 6 MB   (3072x1024)
    bf16* wob = (bf16*)(ws + (14ull << 20));        // 2 MB   (1024x1024)
    bf16* qg  = (bf16*)(ws + (16ull << 20));        // 8 MB   [B,H,T,Dh]
    bf16* kg  = (bf16*)(ws + (24ull << 20));        // 8 MB   [B,H,T,Dh]
    bf16* vt  = (bf16*)(ws + (32ull << 20));        // 8 MB   [B,H,Dh,T]
    bf16* yb  = (bf16*)(ws + (40ull << 20));        // 8 MB   (4096x1024)
    float* ctab = (float*)(ws + (48ull << 20));     // 512 KB (2048x64)
    float* stab = (float*)(ws + (48ull << 20) + (1ull << 19));
    float* mkf  = (float*)(ws + (49ull << 20));     // 16 KB  (2x2048 floats)

    f2b_kernel<<<2048, 256, 0, stream>>>(x, xb, 524288);
    f2b_kernel<<<1536, 256, 0, stream>>>(qkv_w, wqb, 393216);
    f2b_kernel<<<512, 256, 0, stream>>>(out_w, wob, 131072);
    rope_tab_kernel<<<512, 256, 0, stream>>>(ctab, stab);
    maskf_kernel<<<16, 256, 0, stream>>>(amask, mkf);

    gemm_qkv_kernel<<<dim3(32, 24), 256, 0, stream>>>(xb, wqb, qkv_b, ctab, stab, qg, kg, vt);
    attn_kernel<<<dim3(512), 512, 0, stream>>>(qg, kg, vt, mkf, yb);
    gemm_out_kernel<<<dim3(32, 8), 256, 0, stream>>>(yb, wob, out_b, out);
}

// Round 6
// 151.137 us; speedup vs baseline: 1.7561x; 1.2113x over previous
//
#include <hip/hip_runtime.h>
#include <hip/hip_bf16.h>

typedef __bf16 bf16;
typedef __bf16 bf16x4 __attribute__((ext_vector_type(4)));
typedef __bf16 bf16x8 __attribute__((ext_vector_type(8)));
typedef float f32x4 __attribute__((ext_vector_type(4)));

#define T_LEN 2048
#define NHEAD 16
#define DHEAD 64
#define CDIM 1024
#define NB 2

__device__ __forceinline__ void g2l16(const void* g, void* l) {
    __builtin_amdgcn_global_load_lds(
        (const __attribute__((address_space(1))) unsigned int*)g,
        (__attribute__((address_space(3))) unsigned int*)l, 16, 0, 0);
}

// stage a 64-row x 128-byte tile into linear LDS with XOR-swizzled content
// (source pre-swizzle, m173). 512 threads: one 16B chunk each.
__device__ __forceinline__ void stage_swz512(const bf16* __restrict__ g, size_t gstride,
                                             bf16* lds, int t) {
    int off = t * 16;                          // phys byte offset in LDS (0..8191)
    int row = off >> 7;
    int lcol = (off & 127) ^ ((row & 7) << 4); // logical byte col in row
    g2l16(g + (size_t)row * gstride + (lcol >> 1), (char*)lds + off);
}

__device__ __forceinline__ bf16x8 rd_swz(const bf16* lds, int row, int colB) {
    return *(const bf16x8*)((const char*)lds + row * 128 + (colB ^ ((row & 7) << 4)));
}

// ---------- fp32 -> bf16 convert, 8 elems/thread ----------
__global__ __launch_bounds__(256) void f2b_kernel(const float* __restrict__ in,
                                                  bf16* __restrict__ out, int n8) {
    int i = blockIdx.x * 256 + threadIdx.x;
    if (i >= n8) return;
    const float4* p = (const float4*)in + (size_t)i * 2;
    float4 a = p[0], b = p[1];
    bf16x8 o;
    o[0] = (bf16)a.x; o[1] = (bf16)a.y; o[2] = (bf16)a.z; o[3] = (bf16)a.w;
    o[4] = (bf16)b.x; o[5] = (bf16)b.y; o[6] = (bf16)b.z; o[7] = (bf16)b.w;
    ((bf16x8*)out)[i] = o;
}

// ---------- RoPE tables ----------
__global__ __launch_bounds__(256) void rope_tab_kernel(float* __restrict__ ct,
                                                       float* __restrict__ st) {
    int i = blockIdx.x * 256 + threadIdx.x;   // i = t*64 + d
    int t = i >> 6, d = i & 63;
    float ex = (float)(2 * (d & 31)) / 64.0f;
    float inv = powf(10000.0f, -ex);
    float ang = (float)t * inv;
    ct[i] = cosf(ang);
    st[i] = sinf(ang);
}

// ---------- key mask -> additive float ----------
__global__ __launch_bounds__(256) void maskf_kernel(const int* __restrict__ am,
                                                    float* __restrict__ mf) {
    int i = blockIdx.x * 256 + threadIdx.x;   // 0..NB*T_LEN
    mf[i] = (am[i] != 0) ? 0.0f : -1e30f;
}

// ---------- QKV GEMM: fused bias + RoPE; Q,K -> [B][H][T][Dh], V -> [B][H][Dh][T] ----------
__global__ __launch_bounds__(256) void gemm_qkv_kernel(
    const bf16* __restrict__ xb, const bf16* __restrict__ wb,
    const float* __restrict__ bias,
    const float* __restrict__ ct, const float* __restrict__ st,
    bf16* __restrict__ qg, bf16* __restrict__ kg, bf16* __restrict__ vt) {
    __shared__ __align__(16) bf16 smem[2 * 128 * 64];
    bf16* sA = smem;
    bf16* sB = smem + 128 * 64;
    int m0 = blockIdx.x * 128, n0 = blockIdx.y * 128;
    int t = threadIdx.x, w = t >> 6, l = t & 63;
    int wm = w >> 1, wn = w & 1;
    int l15 = l & 15, lhi = l >> 4;
    f32x4 acc[4][4] = {};
    for (int k0 = 0; k0 < CDIM; k0 += 64) {
#pragma unroll
        for (int i = 0; i < 4; i++) {
            int off = i * 4096 + t * 16;              // phys byte offset (0..16383)
            int row = off >> 7;
            int lcol = (off & 127) ^ ((row & 7) << 4);
            g2l16(xb + (size_t)(m0 + row) * CDIM + k0 + (lcol >> 1), (char*)sA + off);
            g2l16(wb + (size_t)(n0 + row) * CDIM + k0 + (lcol >> 1), (char*)sB + off);
        }
        __syncthreads();
#pragma unroll
        for (int ks = 0; ks < 2; ks++) {
            bf16x8 af[4], bfr[4];
#pragma unroll
            for (int mt = 0; mt < 4; mt++)
                af[mt] = rd_swz(sA, wm * 64 + mt * 16 + l15, ks * 64 + lhi * 16);
#pragma unroll
            for (int nt = 0; nt < 4; nt++)
                bfr[nt] = rd_swz(sB, wn * 64 + nt * 16 + l15, ks * 64 + lhi * 16);
#pragma unroll
            for (int mt = 0; mt < 4; mt++)
#pragma unroll
                for (int nt = 0; nt < 4; nt++)
                    acc[mt][nt] = __builtin_amdgcn_mfma_f32_16x16x32_bf16(
                        af[mt], bfr[nt], acc[mt][nt], 0, 0, 0);
        }
        __syncthreads();
    }
    int bb = m0 >> 11, tt0 = m0 & 2047;               // block never crosses batch
    if (n0 >= 2048) {
        // ---- V block: bias + LDS transpose + coalesced [B][H][Dh][T] store ----
        bf16* sT = smem;                              // 64 x 136, reuse staging LDS
#pragma unroll
        for (int pass = 0; pass < 2; pass++) {
            __syncthreads();
            if (wn == pass) {
#pragma unroll
                for (int nt = 0; nt < 4; nt++) {
                    float cb = bias[n0 + pass * 64 + nt * 16 + l15];
#pragma unroll
                    for (int mt = 0; mt < 4; mt++) {
                        bf16x4 pv;
#pragma unroll
                        for (int r = 0; r < 4; r++) pv[r] = (bf16)(acc[mt][nt][r] + cb);
                        *(bf16x4*)(sT + (nt * 16 + l15) * 136 + wm * 64 + mt * 16 + lhi * 4) = pv;
                    }
                }
            }
            __syncthreads();
            int h_p = ((n0 & 1023) >> 6) + pass;
            size_t vbase = ((size_t)(bb * NHEAD + h_p)) * T_LEN * DHEAD + tt0;
#pragma unroll
            for (int c = 0; c < 4; c++) {
                int cid = c * 256 + t;
                int d = cid >> 4, ch = cid & 15;
                *(bf16x8*)(vt + vbase + (size_t)d * T_LEN + ch * 8) =
                    *(const bf16x8*)(sT + d * 136 + ch * 8);
            }
        }
        return;
    }
    // ---- Q/K block: bias + RoPE, [B][H][T][Dh] store ----
    int sec = n0 >> 10;                               // 0=Q 1=K (block-uniform)
    bf16* og = (sec == 0) ? qg : kg;
    float oscale = (sec == 0) ? 0.125f : 1.0f;        // fold 1/sqrt(64) into Q
#pragma unroll
    for (int nt = 0; nt < 4; nt++) {
        int col = n0 + wn * 64 + nt * 16 + l15;
        int cc = col & 1023;
        int h = cc >> 6, d = cc & 63;
        float cb = bias[col];
        size_t hb = ((size_t)(bb * NHEAD + h)) * T_LEN * DHEAD;
#pragma unroll
        for (int mt = 0; mt < 4; mt++) {
#pragma unroll
            for (int r = 0; r < 4; r++) {
                int tt = tt0 + wm * 64 + mt * 16 + lhi * 4 + r;
                float v = acc[mt][nt][r] + cb;
                float p = __shfl_xor(v, 1);
                float cs = ct[tt * 64 + d], sn = st[tt * 64 + d];
                float o = (d & 1) ? (v * cs + p * sn) : (v * cs - p * sn);
                og[hb + (size_t)tt * DHEAD + d] = (bf16)(o * oscale);
            }
        }
    }
}

// ---------- flash attention: swapped QK^T, per-lane-q softmax ----------
__global__ __launch_bounds__(512, 4) void attn_kernel(
    const bf16* __restrict__ qg, const bf16* __restrict__ kg, const bf16* __restrict__ vt,
    const float* __restrict__ maskf, bf16* __restrict__ yb) {
    __shared__ __align__(16) bf16 sK[2][64 * 64];
    __shared__ __align__(16) bf16 sV[2][64 * 64];
    __shared__ __align__(16) bf16 sP[8 * 16 * 72];
    int lin = blockIdx.x;                 // 512 blocks
    int xcd = lin & 7, idx = lin >> 3;    // idx 0..63
    int group = idx >> 4, pos = idx & 15;
    int qt = (pos & 1) ? (pos >> 1) : (15 - (pos >> 1));
    int pair = xcd * 4 + group;           // 0..31
    int h = pair & 15, b = pair >> 4;
    int q0 = qt * 128;
    int t = threadIdx.x, w = t >> 6, l = t & 63;
    int l15 = l & 15, lhi = l >> 4;
    const size_t head_off = ((size_t)(b * NHEAD + h)) * T_LEN * DHEAD;
    const bf16* qb = qg + head_off;
    const bf16* kb = kg + head_off;
    const bf16* vb = vt + head_off;                 // [Dh][T]
    const float* mrow = maskf + b * T_LEN;
    const int wq0 = q0 + w * 16;                    // wave's first q row
    const int qrow_l = wq0 + l15;                   // this lane's q row
    bf16* sPw = sP + w * 1152;
    bf16x8 qf[2];
    {
        qf[0] = *(const bf16x8*)(qb + (size_t)qrow_l * DHEAD + lhi * 8);
        qf[1] = *(const bf16x8*)(qb + (size_t)qrow_l * DHEAD + 32 + lhi * 8);
    }
    float m_ = -1e30f, ls = 0.f;                    // per-lane (q = l15)
    f32x4 accy[4] = {};
    stage_swz512(kb, DHEAD, sK[0], t);
    stage_swz512(vb, T_LEN, sV[0], t);
    __syncthreads();
    int cur = 0;
    const int kv_end = q0 + 64;                     // covers rows up to q0+127
    for (int kv0 = 0; kv0 <= kv_end; kv0 += 64) {
        if (kv0 + 64 <= kv_end) {                   // prefetch next tile
            stage_swz512(kb + (size_t)(kv0 + 64) * DHEAD, DHEAD, sK[cur ^ 1], t);
            stage_swz512(vb + (kv0 + 64), T_LEN, sV[cur ^ 1], t);
        }
        if (kv0 <= wq0 + 15) {                      // wave has unmasked work
            float4 mqv[4];
#pragma unroll
            for (int c = 0; c < 4; c++)
                mqv[c] = *(const float4*)(mrow + kv0 + c * 16 + lhi * 4);
            // S^T = K Q^T: lane holds q = l15, kv = c*16 + lhi*4 + r
            f32x4 s[4] = {};
            __builtin_amdgcn_s_setprio(1);
#pragma unroll
            for (int c = 0; c < 4; c++)
#pragma unroll
                for (int ks = 0; ks < 2; ks++) {
                    bf16x8 kf = rd_swz(sK[cur], c * 16 + l15, ks * 64 + lhi * 16);
                    s[c] = __builtin_amdgcn_mfma_f32_16x16x32_bf16(kf, qf[ks], s[c], 0, 0, 0);
                }
            __builtin_amdgcn_s_setprio(0);
            bool diag = (kv0 + 63 > wq0);           // tile crosses this strip's diagonal
            float mx = -1e30f;
#pragma unroll
            for (int c = 0; c < 4; c++) {
                const float* mp = (const float*)&mqv[c];
#pragma unroll
                for (int r = 0; r < 4; r++) {
                    float sv = s[c][r] + mp[r];
                    if (diag && (kv0 + c * 16 + lhi * 4 + r > qrow_l)) sv = -1e30f;
                    s[c][r] = sv;
                    mx = fmaxf(mx, sv);
                }
            }
            mx = fmaxf(mx, __shfl_xor(mx, 16));
            mx = fmaxf(mx, __shfl_xor(mx, 32));
            bool noresc = __all(mx <= m_ + 8.f);    // defer-max (T13, THR=8)
            float mn = m_, scf = 1.f;
            if (!noresc) {
                mn = fmaxf(m_, mx);
                scf = __expf(m_ - mn);
                m_ = mn;
            }
            float rs = 0.f;
#pragma unroll
            for (int c = 0; c < 4; c++)
#pragma unroll
                for (int r = 0; r < 4; r++) {
                    float pp = __expf(s[c][r] - mn);
                    s[c][r] = pp;
                    rs += pp;
                }
            rs += __shfl_xor(rs, 16);
            rs += __shfl_xor(rs, 32);
            if (noresc) {
                ls += rs;
            } else {
                ls = ls * scf + rs;
#pragma unroll
                for (int r = 0; r < 4; r++) {
                    float sr = __shfl(scf, (l & 48) + lhi * 4 + r);
#pragma unroll
                    for (int dt = 0; dt < 4; dt++) accy[dt][r] *= sr;
                }
            }
            // P -> sP[q=l15][kv], 4x ds_write_b64 (kv r=0..3 contiguous)
#pragma unroll
            for (int c = 0; c < 4; c++) {
                bf16x4 pv;
#pragma unroll
                for (int r = 0; r < 4; r++) pv[r] = (bf16)s[c][r];
                *(bf16x4*)(sPw + l15 * 72 + c * 16 + lhi * 4) = pv;
            }
            __builtin_amdgcn_s_setprio(1);
#pragma unroll
            for (int ks = 0; ks < 2; ks++) {
                bf16x8 pf = *(const bf16x8*)(sPw + l15 * 72 + ks * 32 + lhi * 8);
#pragma unroll
                for (int dt = 0; dt < 4; dt++) {
                    bf16x8 vf = rd_swz(sV[cur], dt * 16 + l15, ks * 64 + lhi * 16);
                    accy[dt] = __builtin_amdgcn_mfma_f32_16x16x32_bf16(pf, vf, accy[dt], 0, 0, 0);
                }
            }
            __builtin_amdgcn_s_setprio(0);
        }
        __syncthreads();
        cur ^= 1;
    }
#pragma unroll
    for (int r = 0; r < 4; r++) {
        float lsr = __shfl(ls, (l & 48) + lhi * 4 + r);
        float inv = lsr > 0.f ? 1.0f / lsr : 0.0f;
        int rowt = wq0 + lhi * 4 + r;
        size_t obase = ((size_t)(b * T_LEN + rowt)) * CDIM + (size_t)h * DHEAD;
#pragma unroll
        for (int dt = 0; dt < 4; dt++)
            yb[obase + dt * 16 + l15] = (bf16)(accy[dt][r] * inv);
    }
}

// ---------- output GEMM ----------
__global__ __launch_bounds__(256) void gemm_out_kernel(
    const bf16* __restrict__ yb, const bf16* __restrict__ wb,
    const float* __restrict__ bias, float* __restrict__ out) {
    __shared__ __align__(16) bf16 sA[128 * 64];
    __shared__ __align__(16) bf16 sB[128 * 64];
    int m0 = blockIdx.x * 128, n0 = blockIdx.y * 128;
    int t = threadIdx.x, w = t >> 6, l = t & 63;
    int wm = w >> 1, wn = w & 1;
    int l15 = l & 15, lhi = l >> 4;
    f32x4 acc[4][4] = {};
    for (int k0 = 0; k0 < CDIM; k0 += 64) {
#pragma unroll
        for (int i = 0; i < 4; i++) {
            int off = i * 4096 + t * 16;
            int row = off >> 7;
            int lcol = (off & 127) ^ ((row & 7) << 4);
            g2l16(yb + (size_t)(m0 + row) * CDIM + k0 + (lcol >> 1), (char*)sA + off);
            g2l16(wb + (size_t)(n0 + row) * CDIM + k0 + (lcol >> 1), (char*)sB + off);
        }
        __syncthreads();
#pragma unroll
        for (int ks = 0; ks < 2; ks++) {
            bf16x8 af[4], bfr[4];
#pragma unroll
            for (int mt = 0; mt < 4; mt++)
                af[mt] = rd_swz(sA, wm * 64 + mt * 16 + l15, ks * 64 + lhi * 16);
#pragma unroll
            for (int nt = 0; nt < 4; nt++)
                bfr[nt] = rd_swz(sB, wn * 64 + nt * 16 + l15, ks * 64 + lhi * 16);
#pragma unroll
            for (int mt = 0; mt < 4; mt++)
#pragma unroll
                for (int nt = 0; nt < 4; nt++)
                    acc[mt][nt] = __builtin_amdgcn_mfma_f32_16x16x32_bf16(
                        af[mt], bfr[nt], acc[mt][nt], 0, 0, 0);
        }
        __syncthreads();
    }
#pragma unroll
    for (int nt = 0; nt < 4; nt++) {
        int col = n0 + wn * 64 + nt * 16 + l15;
        float cb = bias[col];
#pragma unroll
        for (int mt = 0; mt < 4; mt++) {
#pragma unroll
            for (int r = 0; r < 4; r++) {
                int rowm = m0 + wm * 64 + mt * 16 + lhi * 4 + r;
                out[(size_t)rowm * CDIM + col] = acc[mt][nt][r] + cb;
            }
        }
    }
}

extern "C" void kernel_launch(void* const* d_in, const int* in_sizes, int n_in,
                              void* d_out, int out_size, void* d_ws, size_t ws_size,
                              hipStream_t stream) {
    const float* x      = (const float*)d_in[0];
    const int*   amask  = (const int*)d_in[1];
    const float* qkv_w  = (const float*)d_in[2];
    const float* qkv_b  = (const float*)d_in[3];
    const float* out_w  = (const float*)d_in[4];
    const float* out_b  = (const float*)d_in[5];
    float* out = (float*)d_out;

    char* ws = (char*)d_ws;
    bf16* xb  = (bf16*)(ws);                        // 8 MB   (4096x1024)
    bf16* wqb = (bf16*)(ws + (8ull  << 20));        // 6 MB   (3072x1024)
    bf16* wob = (bf16*)(ws + (14ull << 20));        // 2 MB   (1024x1024)
    bf16* qg  = (bf16*)(ws + (16ull << 20));        // 8 MB   [B,H,T,Dh]
    bf16* kg  = (bf16*)(ws + (24ull << 20));        // 8 MB   [B,H,T,Dh]
    bf16* vt  = (bf16*)(ws + (32ull << 20));        // 8 MB   [B,H,Dh,T]
    bf16* yb  = (bf16*)(ws + (40ull << 20));        // 8 MB   (4096x1024)
    float* ctab = (float*)(ws + (48ull << 20));     // 512 KB (2048x64)
    float* stab = (float*)(ws + (48ull << 20) + (1ull << 19));
    float* mkf  = (float*)(ws + (49ull << 20));     // 16 KB  (2x2048 floats)

    f2b_kernel<<<2048, 256, 0, stream>>>(x, xb, 524288);
    f2b_kernel<<<1536, 256, 0, stream>>>(qkv_w, wqb, 393216);
    f2b_kernel<<<512, 256, 0, stream>>>(out_w, wob, 131072);
    rope_tab_kernel<<<512, 256, 0, stream>>>(ctab, stab);
    maskf_kernel<<<16, 256, 0, stream>>>(amask, mkf);

    gemm_qkv_kernel<<<dim3(32, 24), 256, 0, stream>>>(xb, wqb, qkv_b, ctab, stab, qg, kg, vt);
    attn_kernel<<<dim3(512), 512, 0, stream>>>(qg, kg, vt, mkf, yb);
    gemm_out_kernel<<<dim3(32, 8), 256, 0, stream>>>(yb, wob, out_b, out);
}

// Round 7
// 141.295 us; speedup vs baseline: 1.8785x; 1.0697x over previous
//
#include <hip/hip_runtime.h>
#include <hip/hip_bf16.h>

typedef __bf16 bf16;
typedef __bf16 bf16x4 __attribute__((ext_vector_type(4)));
typedef __bf16 bf16x8 __attribute__((ext_vector_type(8)));
typedef float f32x4 __attribute__((ext_vector_type(4)));

#define T_LEN 2048
#define NHEAD 16
#define DHEAD 64
#define CDIM 1024
#define NB 2

__device__ __forceinline__ void g2l16(const void* g, void* l) {
    __builtin_amdgcn_global_load_lds(
        (const __attribute__((address_space(1))) unsigned int*)g,
        (__attribute__((address_space(3))) unsigned int*)l, 16, 0, 0);
}

// native 2^x (v_exp_f32): inputs are base-2 logits
__device__ __forceinline__ float fexp2(float x) {
    float r;
    asm("v_exp_f32 %0, %1" : "=v"(r) : "v"(x));
    return r;
}

// stage a 64-row x 128-byte tile into linear LDS with XOR-swizzled content
// (source pre-swizzle, m173). 512 threads: one 16B chunk each.
__device__ __forceinline__ void stage_swz512(const bf16* __restrict__ g, size_t gstride,
                                             bf16* lds, int t) {
    int off = t * 16;                          // phys byte offset in LDS (0..8191)
    int row = off >> 7;
    int lcol = (off & 127) ^ ((row & 7) << 4); // logical byte col in row
    g2l16(g + (size_t)row * gstride + (lcol >> 1), (char*)lds + off);
}

__device__ __forceinline__ bf16x8 rd_swz(const bf16* lds, int row, int colB) {
    return *(const bf16x8*)((const char*)lds + row * 128 + (colB ^ ((row & 7) << 4)));
}

// ---------- fp32 -> bf16 convert, 8 elems/thread ----------
__global__ __launch_bounds__(256) void f2b_kernel(const float* __restrict__ in,
                                                  bf16* __restrict__ out, int n8) {
    int i = blockIdx.x * 256 + threadIdx.x;
    if (i >= n8) return;
    const float4* p = (const float4*)in + (size_t)i * 2;
    float4 a = p[0], b = p[1];
    bf16x8 o;
    o[0] = (bf16)a.x; o[1] = (bf16)a.y; o[2] = (bf16)a.z; o[3] = (bf16)a.w;
    o[4] = (bf16)b.x; o[5] = (bf16)b.y; o[6] = (bf16)b.z; o[7] = (bf16)b.w;
    ((bf16x8*)out)[i] = o;
}

// ---------- RoPE tables ----------
__global__ __launch_bounds__(256) void rope_tab_kernel(float* __restrict__ ct,
                                                       float* __restrict__ st) {
    int i = blockIdx.x * 256 + threadIdx.x;   // i = t*64 + d
    int t = i >> 6, d = i & 63;
    float ex = (float)(2 * (d & 31)) / 64.0f;
    float inv = powf(10000.0f, -ex);
    float ang = (float)t * inv;
    ct[i] = cosf(ang);
    st[i] = sinf(ang);
}

// ---------- key mask -> additive float ----------
__global__ __launch_bounds__(256) void maskf_kernel(const int* __restrict__ am,
                                                    float* __restrict__ mf) {
    int i = blockIdx.x * 256 + threadIdx.x;   // 0..NB*T_LEN
    mf[i] = (am[i] != 0) ? 0.0f : -1e30f;
}

// ---------- QKV GEMM: fused bias + RoPE; Q,K -> [B][H][T][Dh], V -> [B][H][Dh][T] ----------
__global__ __launch_bounds__(256) void gemm_qkv_kernel(
    const bf16* __restrict__ xb, const bf16* __restrict__ wb,
    const float* __restrict__ bias,
    const float* __restrict__ ct, const float* __restrict__ st,
    bf16* __restrict__ qg, bf16* __restrict__ kg, bf16* __restrict__ vt) {
    __shared__ __align__(16) bf16 smem[2 * 128 * 64];
    bf16* sA = smem;
    bf16* sB = smem + 128 * 64;
    int m0 = blockIdx.x * 128, n0 = blockIdx.y * 128;
    int t = threadIdx.x, w = t >> 6, l = t & 63;
    int wm = w >> 1, wn = w & 1;
    int l15 = l & 15, lhi = l >> 4;
    f32x4 acc[4][4] = {};
    for (int k0 = 0; k0 < CDIM; k0 += 64) {
#pragma unroll
        for (int i = 0; i < 4; i++) {
            int off = i * 4096 + t * 16;              // phys byte offset (0..16383)
            int row = off >> 7;
            int lcol = (off & 127) ^ ((row & 7) << 4);
            g2l16(xb + (size_t)(m0 + row) * CDIM + k0 + (lcol >> 1), (char*)sA + off);
            g2l16(wb + (size_t)(n0 + row) * CDIM + k0 + (lcol >> 1), (char*)sB + off);
        }
        __syncthreads();
#pragma unroll
        for (int ks = 0; ks < 2; ks++) {
            bf16x8 af[4], bfr[4];
#pragma unroll
            for (int mt = 0; mt < 4; mt++)
                af[mt] = rd_swz(sA, wm * 64 + mt * 16 + l15, ks * 64 + lhi * 16);
#pragma unroll
            for (int nt = 0; nt < 4; nt++)
                bfr[nt] = rd_swz(sB, wn * 64 + nt * 16 + l15, ks * 64 + lhi * 16);
#pragma unroll
            for (int mt = 0; mt < 4; mt++)
#pragma unroll
                for (int nt = 0; nt < 4; nt++)
                    acc[mt][nt] = __builtin_amdgcn_mfma_f32_16x16x32_bf16(
                        af[mt], bfr[nt], acc[mt][nt], 0, 0, 0);
        }
        __syncthreads();
    }
    int bb = m0 >> 11, tt0 = m0 & 2047;               // block never crosses batch
    if (n0 >= 2048) {
        // ---- V block: bias + LDS transpose + coalesced [B][H][Dh][T] store ----
        bf16* sT = smem;                              // 64 x 136, reuse staging LDS
#pragma unroll
        for (int pass = 0; pass < 2; pass++) {
            __syncthreads();
            if (wn == pass) {
#pragma unroll
                for (int nt = 0; nt < 4; nt++) {
                    float cb = bias[n0 + pass * 64 + nt * 16 + l15];
#pragma unroll
                    for (int mt = 0; mt < 4; mt++) {
                        bf16x4 pv;
#pragma unroll
                        for (int r = 0; r < 4; r++) pv[r] = (bf16)(acc[mt][nt][r] + cb);
                        *(bf16x4*)(sT + (nt * 16 + l15) * 136 + wm * 64 + mt * 16 + lhi * 4) = pv;
                    }
                }
            }
            __syncthreads();
            int h_p = ((n0 & 1023) >> 6) + pass;
            size_t vbase = ((size_t)(bb * NHEAD + h_p)) * T_LEN * DHEAD + tt0;
#pragma unroll
            for (int c = 0; c < 4; c++) {
                int cid = c * 256 + t;
                int d = cid >> 4, ch = cid & 15;
                *(bf16x8*)(vt + vbase + (size_t)d * T_LEN + ch * 8) =
                    *(const bf16x8*)(sT + d * 136 + ch * 8);
            }
        }
        return;
    }
    // ---- Q/K block: bias + RoPE, [B][H][T][Dh] store ----
    int sec = n0 >> 10;                               // 0=Q 1=K (block-uniform)
    bf16* og = (sec == 0) ? qg : kg;
    // Q: fold 1/sqrt(64) AND log2(e) (softmax runs in base-2)
    float oscale = (sec == 0) ? 0.125f * 1.44269504f : 1.0f;
#pragma unroll
    for (int nt = 0; nt < 4; nt++) {
        int col = n0 + wn * 64 + nt * 16 + l15;
        int cc = col & 1023;
        int h = cc >> 6, d = cc & 63;
        float cb = bias[col];
        size_t hb = ((size_t)(bb * NHEAD + h)) * T_LEN * DHEAD;
#pragma unroll
        for (int mt = 0; mt < 4; mt++) {
#pragma unroll
            for (int r = 0; r < 4; r++) {
                int tt = tt0 + wm * 64 + mt * 16 + lhi * 4 + r;
                float v = acc[mt][nt][r] + cb;
                float p = __shfl_xor(v, 1);
                float cs = ct[tt * 64 + d], sn = st[tt * 64 + d];
                float o = (d & 1) ? (v * cs + p * sn) : (v * cs - p * sn);
                og[hb + (size_t)tt * DHEAD + d] = (bf16)(o * oscale);
            }
        }
    }
}

// ---------- flash attention: swapped QK^T, per-lane-q softmax, base-2 ----------
__global__ __launch_bounds__(512, 4) void attn_kernel(
    const bf16* __restrict__ qg, const bf16* __restrict__ kg, const bf16* __restrict__ vt,
    const float* __restrict__ maskf, bf16* __restrict__ yb) {
    __shared__ __align__(16) bf16 sK[2][64 * 64];
    __shared__ __align__(16) bf16 sV[2][64 * 64];
    __shared__ __align__(16) bf16 sP[8 * 16 * 72];
    // XCD-aware remap. CU c runs blocks lin=c and lin=c+256 (idx differs by 32
    // -> group differs by 2, pos identical). Flip qt on group&2 so every CU
    // gets (qt, 15-qt): (2qt+2)+(2(15-qt)+2) = 34 kv-iters, exactly uniform.
    int lin = blockIdx.x;                 // 512 blocks
    int xcd = lin & 7, idx = lin >> 3;    // idx 0..63
    int group = idx >> 4, pos = idx & 15;
    int qt0 = (pos & 1) ? (pos >> 1) : (15 - (pos >> 1));
    int qt = (group & 2) ? (15 - qt0) : qt0;
    int pair = xcd * 4 + group;           // 0..31
    int h = pair & 15, b = pair >> 4;
    int q0 = qt * 128;
    int t = threadIdx.x, w = t >> 6, l = t & 63;
    int l15 = l & 15, lhi = l >> 4;
    const size_t head_off = ((size_t)(b * NHEAD + h)) * T_LEN * DHEAD;
    const bf16* qb = qg + head_off;
    const bf16* kb = kg + head_off;
    const bf16* vb = vt + head_off;                 // [Dh][T]
    const float* mrow = maskf + b * T_LEN;
    const int wq0 = q0 + w * 16;                    // wave's first q row
    const int qrow_l = wq0 + l15;                   // this lane's q row
    bf16* sPw = sP + w * 1152;
    bf16x8 qf[2];
    {
        qf[0] = *(const bf16x8*)(qb + (size_t)qrow_l * DHEAD + lhi * 8);
        qf[1] = *(const bf16x8*)(qb + (size_t)qrow_l * DHEAD + 32 + lhi * 8);
    }
    float m_ = -1e30f, ls = 0.f;                    // per-lane (q = l15), base-2
    f32x4 accy[4] = {};
    stage_swz512(kb, DHEAD, sK[0], t);
    stage_swz512(vb, T_LEN, sV[0], t);
    __syncthreads();
    int cur = 0;
    const int kv_end = q0 + 64;                     // covers rows up to q0+127
    for (int kv0 = 0; kv0 <= kv_end; kv0 += 64) {
        if (kv0 + 64 <= kv_end) {                   // prefetch next tile
            stage_swz512(kb + (size_t)(kv0 + 64) * DHEAD, DHEAD, sK[cur ^ 1], t);
            stage_swz512(vb + (kv0 + 64), T_LEN, sV[cur ^ 1], t);
        }
        if (kv0 <= wq0 + 15) {                      // wave has unmasked work
            float4 mqv[4];
#pragma unroll
            for (int c = 0; c < 4; c++)
                mqv[c] = *(const float4*)(mrow + kv0 + c * 16 + lhi * 4);
            // S^T = K Q^T: lane holds q = l15, kv = c*16 + lhi*4 + r
            f32x4 s[4] = {};
            __builtin_amdgcn_s_setprio(1);
#pragma unroll
            for (int c = 0; c < 4; c++)
#pragma unroll
                for (int ks = 0; ks < 2; ks++) {
                    bf16x8 kf = rd_swz(sK[cur], c * 16 + l15, ks * 64 + lhi * 16);
                    s[c] = __builtin_amdgcn_mfma_f32_16x16x32_bf16(kf, qf[ks], s[c], 0, 0, 0);
                }
            __builtin_amdgcn_s_setprio(0);
            bool diag = (kv0 + 63 > wq0);           // tile crosses this strip's diagonal
            float mx = -1e30f;
#pragma unroll
            for (int c = 0; c < 4; c++) {
                const float* mp = (const float*)&mqv[c];
#pragma unroll
                for (int r = 0; r < 4; r++) {
                    float sv = s[c][r] + mp[r];
                    if (diag && (kv0 + c * 16 + lhi * 4 + r > qrow_l)) sv = -1e30f;
                    s[c][r] = sv;
                    mx = fmaxf(mx, sv);
                }
            }
            mx = fmaxf(mx, __shfl_xor(mx, 16));
            mx = fmaxf(mx, __shfl_xor(mx, 32));
            bool noresc = __all(mx <= m_ + 8.f);    // defer-max (T13), base-2 units
            float mn = m_, scf = 1.f;
            if (!noresc) {
                mn = fmaxf(m_, mx);
                scf = fexp2(m_ - mn);
                m_ = mn;
            }
            float rs = 0.f;
#pragma unroll
            for (int c = 0; c < 4; c++)
#pragma unroll
                for (int r = 0; r < 4; r++) {
                    float pp = fexp2(s[c][r] - mn);
                    s[c][r] = pp;
                    rs += pp;
                }
            rs += __shfl_xor(rs, 16);
            rs += __shfl_xor(rs, 32);
            if (noresc) {
                ls += rs;
            } else {
                ls = ls * scf + rs;
#pragma unroll
                for (int r = 0; r < 4; r++) {
                    float sr = __shfl(scf, (l & 48) + lhi * 4 + r);
#pragma unroll
                    for (int dt = 0; dt < 4; dt++) accy[dt][r] *= sr;
                }
            }
            // P -> sP[q=l15][kv], 4x ds_write_b64 (kv r=0..3 contiguous)
#pragma unroll
            for (int c = 0; c < 4; c++) {
                bf16x4 pv;
#pragma unroll
                for (int r = 0; r < 4; r++) pv[r] = (bf16)s[c][r];
                *(bf16x4*)(sPw + l15 * 72 + c * 16 + lhi * 4) = pv;
            }
            __builtin_amdgcn_s_setprio(1);
#pragma unroll
            for (int ks = 0; ks < 2; ks++) {
                bf16x8 pf = *(const bf16x8*)(sPw + l15 * 72 + ks * 32 + lhi * 8);
#pragma unroll
                for (int dt = 0; dt < 4; dt++) {
                    bf16x8 vf = rd_swz(sV[cur], dt * 16 + l15, ks * 64 + lhi * 16);
                    accy[dt] = __builtin_amdgcn_mfma_f32_16x16x32_bf16(pf, vf, accy[dt], 0, 0, 0);
                }
            }
            __builtin_amdgcn_s_setprio(0);
        }
        __syncthreads();
        cur ^= 1;
    }
#pragma unroll
    for (int r = 0; r < 4; r++) {
        float lsr = __shfl(ls, (l & 48) + lhi * 4 + r);
        float inv = lsr > 0.f ? 1.0f / lsr : 0.0f;
        int rowt = wq0 + lhi * 4 + r;
        size_t obase = ((size_t)(b * T_LEN + rowt)) * CDIM + (size_t)h * DHEAD;
#pragma unroll
        for (int dt = 0; dt < 4; dt++)
            yb[obase + dt * 16 + l15] = (bf16)(accy[dt][r] * inv);
    }
}

// ---------- output GEMM ----------
__global__ __launch_bounds__(256) void gemm_out_kernel(
    const bf16* __restrict__ yb, const bf16* __restrict__ wb,
    const float* __restrict__ bias, float* __restrict__ out) {
    __shared__ __align__(16) bf16 sA[128 * 64];
    __shared__ __align__(16) bf16 sB[128 * 64];
    int m0 = blockIdx.x * 128, n0 = blockIdx.y * 128;
    int t = threadIdx.x, w = t >> 6, l = t & 63;
    int wm = w >> 1, wn = w & 1;
    int l15 = l & 15, lhi = l >> 4;
    f32x4 acc[4][4] = {};
    for (int k0 = 0; k0 < CDIM; k0 += 64) {
#pragma unroll
        for (int i = 0; i < 4; i++) {
            int off = i * 4096 + t * 16;
            int row = off >> 7;
            int lcol = (off & 127) ^ ((row & 7) << 4);
            g2l16(yb + (size_t)(m0 + row) * CDIM + k0 + (lcol >> 1), (char*)sA + off);
            g2l16(wb + (size_t)(n0 + row) * CDIM + k0 + (lcol >> 1), (char*)sB + off);
        }
        __syncthreads();
#pragma unroll
        for (int ks = 0; ks < 2; ks++) {
            bf16x8 af[4], bfr[4];
#pragma unroll
            for (int mt = 0; mt < 4; mt++)
                af[mt] = rd_swz(sA, wm * 64 + mt * 16 + l15, ks * 64 + lhi * 16);
#pragma unroll
            for (int nt = 0; nt < 4; nt++)
                bfr[nt] = rd_swz(sB, wn * 64 + nt * 16 + l15, ks * 64 + lhi * 16);
#pragma unroll
            for (int mt = 0; mt < 4; mt++)
#pragma unroll
                for (int nt = 0; nt < 4; nt++)
                    acc[mt][nt] = __builtin_amdgcn_mfma_f32_16x16x32_bf16(
                        af[mt], bfr[nt], acc[mt][nt], 0, 0, 0);
        }
        __syncthreads();
    }
#pragma unroll
    for (int nt = 0; nt < 4; nt++) {
        int col = n0 + wn * 64 + nt * 16 + l15;
        float cb = bias[col];
#pragma unroll
        for (int mt = 0; mt < 4; mt++) {
#pragma unroll
            for (int r = 0; r < 4; r++) {
                int rowm = m0 + wm * 64 + mt * 16 + lhi * 4 + r;
                out[(size_t)rowm * CDIM + col] = acc[mt][nt][r] + cb;
            }
        }
    }
}

extern "C" void kernel_launch(void* const* d_in, const int* in_sizes, int n_in,
                              void* d_out, int out_size, void* d_ws, size_t ws_size,
                              hipStream_t stream) {
    const float* x      = (const float*)d_in[0];
    const int*   amask  = (const int*)d_in[1];
    const float* qkv_w  = (const float*)d_in[2];
    const float* qkv_b  = (const float*)d_in[3];
    const float* out_w  = (const float*)d_in[4];
    const float* out_b  = (const float*)d_in[5];
    float* out = (float*)d_out;

    char* ws = (char*)d_ws;
    bf16* xb  = (bf16*)(ws);                        // 8 MB   (4096x1024)
    bf16* wqb = (bf16*)(ws + (8ull  << 20));        // 6 MB   (3072x1024)
    bf16* wob = (bf16*)(ws + (14ull << 20));        // 2 MB   (1024x1024)
    bf16* qg  = (bf16*)(ws + (16ull << 20));        // 8 MB   [B,H,T,Dh]
    bf16* kg  = (bf16*)(ws + (24ull << 20));        // 8 MB   [B,H,T,Dh]
    bf16* vt  = (bf16*)(ws + (32ull << 20));        // 8 MB   [B,H,Dh,T]
    bf16* yb  = (bf16*)(ws + (40ull << 20));        // 8 MB   (4096x1024)
    float* ctab = (float*)(ws + (48ull << 20));     // 512 KB (2048x64)
    float* stab = (float*)(ws + (48ull << 20) + (1ull << 19));
    float* mkf  = (float*)(ws + (49ull << 20));     // 16 KB  (2x2048 floats)

    f2b_kernel<<<2048, 256, 0, stream>>>(x, xb, 524288);
    f2b_kernel<<<1536, 256, 0, stream>>>(qkv_w, wqb, 393216);
    f2b_kernel<<<512, 256, 0, stream>>>(out_w, wob, 131072);
    rope_tab_kernel<<<512, 256, 0, stream>>>(ctab, stab);
    maskf_kernel<<<16, 256, 0, stream>>>(amask, mkf);

    gemm_qkv_kernel<<<dim3(32, 24), 256, 0, stream>>>(xb, wqb, qkv_b, ctab, stab, qg, kg, vt);
    attn_kernel<<<dim3(512), 512, 0, stream>>>(qg, kg, vt, mkf, yb);
    gemm_out_kernel<<<dim3(32, 8), 256, 0, stream>>>(yb, wob, out_b, out);
}

// Round 8
// 134.781 us; speedup vs baseline: 1.9693x; 1.0483x over previous
//
#include <hip/hip_runtime.h>
#include <hip/hip_bf16.h>

typedef __bf16 bf16;
typedef __bf16 bf16x4 __attribute__((ext_vector_type(4)));
typedef __bf16 bf16x8 __attribute__((ext_vector_type(8)));
typedef float f32x4 __attribute__((ext_vector_type(4)));

#define T_LEN 2048
#define NHEAD 16
#define DHEAD 64
#define CDIM 1024
#define NB 2

__device__ __forceinline__ void g2l16(const void* g, void* l) {
    __builtin_amdgcn_global_load_lds(
        (const __attribute__((address_space(1))) unsigned int*)g,
        (__attribute__((address_space(3))) unsigned int*)l, 16, 0, 0);
}

// native 2^x (v_exp_f32): inputs are base-2 logits
__device__ __forceinline__ float fexp2(float x) {
    float r;
    asm("v_exp_f32 %0, %1" : "=v"(r) : "v"(x));
    return r;
}

// stage a 64-row x 128-byte tile into linear LDS with XOR-swizzled content
// (source pre-swizzle, m173). 512 threads: one 16B chunk each.
__device__ __forceinline__ void stage_swz512(const bf16* __restrict__ g, size_t gstride,
                                             bf16* lds, int t) {
    int off = t * 16;                          // phys byte offset in LDS (0..8191)
    int row = off >> 7;
    int lcol = (off & 127) ^ ((row & 7) << 4); // logical byte col in row
    g2l16(g + (size_t)row * gstride + (lcol >> 1), (char*)lds + off);
}

__device__ __forceinline__ bf16x8 rd_swz(const bf16* lds, int row, int colB) {
    return *(const bf16x8*)((const char*)lds + row * 128 + (colB ^ ((row & 7) << 4)));
}

// ---------- fused prep: fp32->bf16 x3 + RoPE tables + mask ----------
__global__ __launch_bounds__(256) void prep_kernel(
    const float* __restrict__ x, const float* __restrict__ qkv_w,
    const float* __restrict__ out_w, const int* __restrict__ am,
    bf16* __restrict__ xb, bf16* __restrict__ wqb, bf16* __restrict__ wob,
    float* __restrict__ ct, float* __restrict__ st, float* __restrict__ mf) {
    int bid = blockIdx.x;
    if (bid < 4096) {                         // converts (block-uniform section)
        int i = bid * 256 + threadIdx.x;
        const float* src; bf16* dst; int j;
        if (i < 524288)      { src = x;     dst = xb;  j = i; }
        else if (i < 917504) { src = qkv_w; dst = wqb; j = i - 524288; }
        else                 { src = out_w; dst = wob; j = i - 917504; }
        const float4* p = (const float4*)src + (size_t)j * 2;
        float4 a = p[0], b = p[1];
        bf16x8 o;
        o[0] = (bf16)a.x; o[1] = (bf16)a.y; o[2] = (bf16)a.z; o[3] = (bf16)a.w;
        o[4] = (bf16)b.x; o[5] = (bf16)b.y; o[6] = (bf16)b.z; o[7] = (bf16)b.w;
        ((bf16x8*)dst)[j] = o;
    } else if (bid < 4608) {                  // RoPE tables
        int i = (bid - 4096) * 256 + threadIdx.x;   // i = t*64 + d
        int t = i >> 6, d = i & 63;
        float ex = (float)(2 * (d & 31)) / 64.0f;
        float inv = powf(10000.0f, -ex);
        float ang = (float)t * inv;
        ct[i] = cosf(ang);
        st[i] = sinf(ang);
    } else {                                  // key mask -> additive float
        int i = (bid - 4608) * 256 + threadIdx.x;
        mf[i] = (am[i] != 0) ? 0.0f : -1e30f;
    }
}

// ---------- QKV GEMM: fused bias + RoPE; Q,K -> [B][H][T][Dh], V -> [B][H][Dh][T] ----------
__global__ __launch_bounds__(256) void gemm_qkv_kernel(
    const bf16* __restrict__ xb, const bf16* __restrict__ wb,
    const float* __restrict__ bias,
    const float* __restrict__ ct, const float* __restrict__ st,
    bf16* __restrict__ qg, bf16* __restrict__ kg, bf16* __restrict__ vt) {
    __shared__ __align__(16) bf16 smem[2 * 128 * 64];
    bf16* sA = smem;
    bf16* sB = smem + 128 * 64;
    int m0 = blockIdx.x * 128, n0 = blockIdx.y * 128;
    int t = threadIdx.x, w = t >> 6, l = t & 63;
    int wm = w >> 1, wn = w & 1;
    int l15 = l & 15, lhi = l >> 4;
    f32x4 acc[4][4] = {};
    for (int k0 = 0; k0 < CDIM; k0 += 64) {
#pragma unroll
        for (int i = 0; i < 4; i++) {
            int off = i * 4096 + t * 16;              // phys byte offset (0..16383)
            int row = off >> 7;
            int lcol = (off & 127) ^ ((row & 7) << 4);
            g2l16(xb + (size_t)(m0 + row) * CDIM + k0 + (lcol >> 1), (char*)sA + off);
            g2l16(wb + (size_t)(n0 + row) * CDIM + k0 + (lcol >> 1), (char*)sB + off);
        }
        __syncthreads();
#pragma unroll
        for (int ks = 0; ks < 2; ks++) {
            bf16x8 af[4], bfr[4];
#pragma unroll
            for (int mt = 0; mt < 4; mt++)
                af[mt] = rd_swz(sA, wm * 64 + mt * 16 + l15, ks * 64 + lhi * 16);
#pragma unroll
            for (int nt = 0; nt < 4; nt++)
                bfr[nt] = rd_swz(sB, wn * 64 + nt * 16 + l15, ks * 64 + lhi * 16);
#pragma unroll
            for (int mt = 0; mt < 4; mt++)
#pragma unroll
                for (int nt = 0; nt < 4; nt++)
                    acc[mt][nt] = __builtin_amdgcn_mfma_f32_16x16x32_bf16(
                        af[mt], bfr[nt], acc[mt][nt], 0, 0, 0);
        }
        __syncthreads();
    }
    int bb = m0 >> 11, tt0 = m0 & 2047;               // block never crosses batch
    if (n0 >= 2048) {
        // ---- V block: bias + LDS transpose + coalesced [B][H][Dh][T] store ----
        bf16* sT = smem;                              // 64 x 136, reuse staging LDS
#pragma unroll
        for (int pass = 0; pass < 2; pass++) {
            __syncthreads();
            if (wn == pass) {
#pragma unroll
                for (int nt = 0; nt < 4; nt++) {
                    float cb = bias[n0 + pass * 64 + nt * 16 + l15];
#pragma unroll
                    for (int mt = 0; mt < 4; mt++) {
                        bf16x4 pv;
#pragma unroll
                        for (int r = 0; r < 4; r++) pv[r] = (bf16)(acc[mt][nt][r] + cb);
                        *(bf16x4*)(sT + (nt * 16 + l15) * 136 + wm * 64 + mt * 16 + lhi * 4) = pv;
                    }
                }
            }
            __syncthreads();
            int h_p = ((n0 & 1023) >> 6) + pass;
            size_t vbase = ((size_t)(bb * NHEAD + h_p)) * T_LEN * DHEAD + tt0;
#pragma unroll
            for (int c = 0; c < 4; c++) {
                int cid = c * 256 + t;
                int d = cid >> 4, ch = cid & 15;
                *(bf16x8*)(vt + vbase + (size_t)d * T_LEN + ch * 8) =
                    *(const bf16x8*)(sT + d * 136 + ch * 8);
            }
        }
        return;
    }
    // ---- Q/K block: bias + RoPE, [B][H][T][Dh] store ----
    int sec = n0 >> 10;                               // 0=Q 1=K (block-uniform)
    bf16* og = (sec == 0) ? qg : kg;
    // Q: fold 1/sqrt(64) AND log2(e) (softmax runs in base-2)
    float oscale = (sec == 0) ? 0.125f * 1.44269504f : 1.0f;
#pragma unroll
    for (int nt = 0; nt < 4; nt++) {
        int col = n0 + wn * 64 + nt * 16 + l15;
        int cc = col & 1023;
        int h = cc >> 6, d = cc & 63;
        float cb = bias[col];
        size_t hb = ((size_t)(bb * NHEAD + h)) * T_LEN * DHEAD;
#pragma unroll
        for (int mt = 0; mt < 4; mt++) {
#pragma unroll
            for (int r = 0; r < 4; r++) {
                int tt = tt0 + wm * 64 + mt * 16 + lhi * 4 + r;
                float v = acc[mt][nt][r] + cb;
                float p = __shfl_xor(v, 1);
                float cs = ct[tt * 64 + d], sn = st[tt * 64 + d];
                float o = (d & 1) ? (v * cs + p * sn) : (v * cs - p * sn);
                og[hb + (size_t)tt * DHEAD + d] = (bf16)(o * oscale);
            }
        }
    }
}

// ---------- flash attention: swapped QK^T, speculative base-2 softmax ----------
__global__ __launch_bounds__(512, 4) void attn_kernel(
    const bf16* __restrict__ qg, const bf16* __restrict__ kg, const bf16* __restrict__ vt,
    const float* __restrict__ maskf, bf16* __restrict__ yb) {
    __shared__ __align__(16) bf16 sK[2][64 * 64];
    __shared__ __align__(16) bf16 sV[2][64 * 64];
    __shared__ __align__(16) bf16 sP[8 * 16 * 72];
    // XCD-aware remap; qt flipped on group&2 so each CU's pair sums to 34 iters.
    int lin = blockIdx.x;                 // 512 blocks
    int xcd = lin & 7, idx = lin >> 3;    // idx 0..63
    int group = idx >> 4, pos = idx & 15;
    int qt0 = (pos & 1) ? (pos >> 1) : (15 - (pos >> 1));
    int qt = (group & 2) ? (15 - qt0) : qt0;
    int pair = xcd * 4 + group;           // 0..31
    int h = pair & 15, b = pair >> 4;
    int q0 = qt * 128;
    int t = threadIdx.x, w = t >> 6, l = t & 63;
    int l15 = l & 15, lhi = l >> 4;
    const size_t head_off = ((size_t)(b * NHEAD + h)) * T_LEN * DHEAD;
    const bf16* qb = qg + head_off;
    const bf16* kb = kg + head_off;
    const bf16* vb = vt + head_off;                 // [Dh][T]
    const float* mrow = maskf + b * T_LEN;
    const int wq0 = q0 + w * 16;                    // wave's first q row
    const int qrow_l = wq0 + l15;                   // this lane's q row
    bf16* sPw = sP + w * 1152;
    bf16x8 qf[2];
    {
        qf[0] = *(const bf16x8*)(qb + (size_t)qrow_l * DHEAD + lhi * 8);
        qf[1] = *(const bf16x8*)(qb + (size_t)qrow_l * DHEAD + 32 + lhi * 8);
    }
    float m_ = -1e30f, ls = 0.f;                    // per-lane (q = l15), base-2
    f32x4 accy[4] = {};
    stage_swz512(kb, DHEAD, sK[0], t);
    stage_swz512(vb, T_LEN, sV[0], t);
    __syncthreads();
    int cur = 0;
    const int kv_end = q0 + 64;                     // covers rows up to q0+127
    for (int kv0 = 0; kv0 <= kv_end; kv0 += 64) {
        if (kv0 + 64 <= kv_end) {                   // prefetch next tile
            stage_swz512(kb + (size_t)(kv0 + 64) * DHEAD, DHEAD, sK[cur ^ 1], t);
            stage_swz512(vb + (kv0 + 64), T_LEN, sV[cur ^ 1], t);
        }
        if (kv0 <= wq0 + 15) {                      // wave has unmasked work
            float4 mqv[4];
#pragma unroll
            for (int c = 0; c < 4; c++)
                mqv[c] = *(const float4*)(mrow + kv0 + c * 16 + lhi * 4);
            // S^T = K Q^T: lane holds q = l15, kv = c*16 + lhi*4 + r
            f32x4 s[4] = {};
            __builtin_amdgcn_s_setprio(1);
#pragma unroll
            for (int c = 0; c < 4; c++)
#pragma unroll
                for (int ks = 0; ks < 2; ks++) {
                    bf16x8 kf = rd_swz(sK[cur], c * 16 + l15, ks * 64 + lhi * 16);
                    s[c] = __builtin_amdgcn_mfma_f32_16x16x32_bf16(kf, qf[ks], s[c], 0, 0, 0);
                }
            __builtin_amdgcn_s_setprio(0);
            bool diag = (kv0 + 63 > wq0);           // tile crosses this strip's diagonal
            float mxl = -1e30f;
#pragma unroll
            for (int c = 0; c < 4; c++) {
                const float* mp = (const float*)&mqv[c];
#pragma unroll
                for (int r = 0; r < 4; r++) {
                    float sv = s[c][r] + mp[r];
                    if (diag && (kv0 + c * 16 + lhi * 4 + r > qrow_l)) sv = -1e30f;
                    s[c][r] = sv;
                    mxl = fmaxf(mxl, sv);
                }
            }
            if (kv0 == 0) {
                // first tile: non-speculative (m_ = -inf would overflow exp)
                float mx = fmaxf(mxl, __shfl_xor(mxl, 16));
                mx = fmaxf(mx, __shfl_xor(mx, 32));
                m_ = mx;
                float rs = 0.f;
#pragma unroll
                for (int c = 0; c < 4; c++)
#pragma unroll
                    for (int r = 0; r < 4; r++) {
                        float pp = fexp2(s[c][r] - mx);
                        s[c][r] = pp;
                        rs += pp;
                    }
                rs += __shfl_xor(rs, 16);
                rs += __shfl_xor(rs, 32);
                ls = rs;
            } else {
                // speculative: exp with old m_ runs concurrently with mx reduce
                float mx = fmaxf(mxl, __shfl_xor(mxl, 16));
                mx = fmaxf(mx, __shfl_xor(mx, 32));
                float rs = 0.f;
#pragma unroll
                for (int c = 0; c < 4; c++)
#pragma unroll
                    for (int r = 0; r < 4; r++) {
                        float pp = fexp2(s[c][r] - m_);
                        s[c][r] = pp;
                        rs += pp;
                    }
                rs += __shfl_xor(rs, 16);
                rs += __shfl_xor(rs, 32);
                if (__all(mx <= m_ + 8.f)) {        // defer-max (T13), base-2 units
                    ls += rs;
                } else {
                    float mn = fmaxf(m_, mx);
                    float scf = fexp2(m_ - mn);
                    m_ = mn;
#pragma unroll
                    for (int c = 0; c < 4; c++)
#pragma unroll
                        for (int r = 0; r < 4; r++) s[c][r] *= scf;
                    ls = (ls + rs) * scf;
#pragma unroll
                    for (int r = 0; r < 4; r++) {
                        float sr = __shfl(scf, (l & 48) + lhi * 4 + r);
#pragma unroll
                        for (int dt = 0; dt < 4; dt++) accy[dt][r] *= sr;
                    }
                }
            }
            // P -> sP[q=l15][kv], 4x ds_write_b64 (kv r=0..3 contiguous)
#pragma unroll
            for (int c = 0; c < 4; c++) {
                bf16x4 pv;
#pragma unroll
                for (int r = 0; r < 4; r++) pv[r] = (bf16)s[c][r];
                *(bf16x4*)(sPw + l15 * 72 + c * 16 + lhi * 4) = pv;
            }
            __builtin_amdgcn_s_setprio(1);
#pragma unroll
            for (int ks = 0; ks < 2; ks++) {
                bf16x8 pf = *(const bf16x8*)(sPw + l15 * 72 + ks * 32 + lhi * 8);
#pragma unroll
                for (int dt = 0; dt < 4; dt++) {
                    bf16x8 vf = rd_swz(sV[cur], dt * 16 + l15, ks * 64 + lhi * 16);
                    accy[dt] = __builtin_amdgcn_mfma_f32_16x16x32_bf16(pf, vf, accy[dt], 0, 0, 0);
                }
            }
            __builtin_amdgcn_s_setprio(0);
        }
        __syncthreads();
        cur ^= 1;
    }
#pragma unroll
    for (int r = 0; r < 4; r++) {
        float lsr = __shfl(ls, (l & 48) + lhi * 4 + r);
        float inv = lsr > 0.f ? 1.0f / lsr : 0.0f;
        int rowt = wq0 + lhi * 4 + r;
        size_t obase = ((size_t)(b * T_LEN + rowt)) * CDIM + (size_t)h * DHEAD;
#pragma unroll
        for (int dt = 0; dt < 4; dt++)
            yb[obase + dt * 16 + l15] = (bf16)(accy[dt][r] * inv);
    }
}

// ---------- output GEMM ----------
__global__ __launch_bounds__(256) void gemm_out_kernel(
    const bf16* __restrict__ yb, const bf16* __restrict__ wb,
    const float* __restrict__ bias, float* __restrict__ out) {
    __shared__ __align__(16) bf16 sA[128 * 64];
    __shared__ __align__(16) bf16 sB[128 * 64];
    int m0 = blockIdx.x * 128, n0 = blockIdx.y * 128;
    int t = threadIdx.x, w = t >> 6, l = t & 63;
    int wm = w >> 1, wn = w & 1;
    int l15 = l & 15, lhi = l >> 4;
    f32x4 acc[4][4] = {};
    for (int k0 = 0; k0 < CDIM; k0 += 64) {
#pragma unroll
        for (int i = 0; i < 4; i++) {
            int off = i * 4096 + t * 16;
            int row = off >> 7;
            int lcol = (off & 127) ^ ((row & 7) << 4);
            g2l16(yb + (size_t)(m0 + row) * CDIM + k0 + (lcol >> 1), (char*)sA + off);
            g2l16(wb + (size_t)(n0 + row) * CDIM + k0 + (lcol >> 1), (char*)sB + off);
        }
        __syncthreads();
#pragma unroll
        for (int ks = 0; ks < 2; ks++) {
            bf16x8 af[4], bfr[4];
#pragma unroll
            for (int mt = 0; mt < 4; mt++)
                af[mt] = rd_swz(sA, wm * 64 + mt * 16 + l15, ks * 64 + lhi * 16);
#pragma unroll
            for (int nt = 0; nt < 4; nt++)
                bfr[nt] = rd_swz(sB, wn * 64 + nt * 16 + l15, ks * 64 + lhi * 16);
#pragma unroll
            for (int mt = 0; mt < 4; mt++)
#pragma unroll
                for (int nt = 0; nt < 4; nt++)
                    acc[mt][nt] = __builtin_amdgcn_mfma_f32_16x16x32_bf16(
                        af[mt], bfr[nt], acc[mt][nt], 0, 0, 0);
        }
        __syncthreads();
    }
#pragma unroll
    for (int nt = 0; nt < 4; nt++) {
        int col = n0 + wn * 64 + nt * 16 + l15;
        float cb = bias[col];
#pragma unroll
        for (int mt = 0; mt < 4; mt++) {
#pragma unroll
            for (int r = 0; r < 4; r++) {
                int rowm = m0 + wm * 64 + mt * 16 + lhi * 4 + r;
                out[(size_t)rowm * CDIM + col] = acc[mt][nt][r] + cb;
            }
        }
    }
}

extern "C" void kernel_launch(void* const* d_in, const int* in_sizes, int n_in,
                              void* d_out, int out_size, void* d_ws, size_t ws_size,
                              hipStream_t stream) {
    const float* x      = (const float*)d_in[0];
    const int*   amask  = (const int*)d_in[1];
    const float* qkv_w  = (const float*)d_in[2];
    const float* qkv_b  = (const float*)d_in[3];
    const float* out_w  = (const float*)d_in[4];
    const float* out_b  = (const float*)d_in[5];
    float* out = (float*)d_out;

    char* ws = (char*)d_ws;
    bf16* xb  = (bf16*)(ws);                        // 8 MB   (4096x1024)
    bf16* wqb = (bf16*)(ws + (8ull  << 20));        // 6 MB   (3072x1024)
    bf16* wob = (bf16*)(ws + (14ull << 20));        // 2 MB   (1024x1024)
    bf16* qg  = (bf16*)(ws + (16ull << 20));        // 8 MB   [B,H,T,Dh]
    bf16* kg  = (bf16*)(ws + (24ull << 20));        // 8 MB   [B,H,T,Dh]
    bf16* vt  = (bf16*)(ws + (32ull << 20));        // 8 MB   [B,H,Dh,T]
    bf16* yb  = (bf16*)(ws + (40ull << 20));        // 8 MB   (4096x1024)
    float* ctab = (float*)(ws + (48ull << 20));     // 512 KB (2048x64)
    float* stab = (float*)(ws + (48ull << 20) + (1ull << 19));
    float* mkf  = (float*)(ws + (49ull << 20));     // 16 KB  (2x2048 floats)

    prep_kernel<<<4624, 256, 0, stream>>>(x, qkv_w, out_w, amask,
                                          xb, wqb, wob, ctab, stab, mkf);
    gemm_qkv_kernel<<<dim3(32, 24), 256, 0, stream>>>(xb, wqb, qkv_b, ctab, stab, qg, kg, vt);
    attn_kernel<<<dim3(512), 512, 0, stream>>>(qg, kg, vt, mkf, yb);
    gemm_out_kernel<<<dim3(32, 8), 256, 0, stream>>>(yb, wob, out_b, out);
}